// Round 6
// baseline (353.106 us; speedup 1.0000x reference)
//
#include <hip/hip_runtime.h>
#include <math.h>

#define DIM 24
#define HID 256
#define NLO 276
#define NSAMP 4096
// output layout: M [4096*576] | c [4096*24] | g [4096*24]
#define C_OFF 2359296
#define G_OFF 2457600

// workspace layout (float offsets)
#define OFF_W2FH 0          // bf16 hi, W2 MFMA-A frags (65536 sh)   32768 f
#define OFF_W2FL 32768      // bf16 lo
#define OFF_WEFH 65536      // bf16 hi, [WLd;WLo;0] frags (81920 sh) 40960 f
#define OFF_WEFL 106496
#define OFF_W1H16 147456    // f16 hi, W1 frags (8192 sh)            4096 f
#define OFF_W1L16 151552
#define OFF_W2H16 155648    // f16 hi, W2 frags (65536 sh)           32768 f
#define OFF_W2L16 188416
#define OFF_WHH16 221184    // f16 hi, heads (Ld|G|Lo|0) frags       43008 f
#define OFF_WHL16 264192
// transposed per-sample fields [field][4096]
#define OFF_MSKT 307200     // 16 u32 words x 4096
#define OFF_SIGT 372736     // 24 x 4096
#define OFF_LDT  471040     // 24 x 4096
#define OFF_UT   569344     // 24 x 4096
#define OFF_LOT  667648     // 276 x 4096
#define OFF_EBUF 1798144    // [chunk][7200] raw E rows (dld-raw 0..23 | dlo 24..299)

typedef __attribute__((ext_vector_type(8))) short bf16x8;
typedef __attribute__((ext_vector_type(8))) _Float16 f16x8;
typedef __attribute__((ext_vector_type(4))) float f32x4;

__device__ __forceinline__ float leaky(float x){ return x > 0.f ? x : 0.01f*x; }
__device__ __forceinline__ unsigned short f2b(float f){           // fp32 -> bf16 RNE
  unsigned u = __float_as_uint(f);
  return (unsigned short)((u + 0x7FFFu + ((u >> 16) & 1u)) >> 16);
}
__device__ __forceinline__ float b2f(unsigned short h){ return __uint_as_float(((unsigned)h) << 16); }
__device__ __forceinline__ void f2h2(float v, unsigned short* hi, unsigned short* lo){
  _Float16 h = (_Float16)v;
  _Float16 l = (_Float16)((v - (float)h) * 4096.f);
  *hi = *(unsigned short*)&h; *lo = *(unsigned short*)&l;
}

// ---------------- Kernel 0: fragment packing ----------------
__global__ __launch_bounds__(256) void k0_prep(
    const float* __restrict__ W1, const float* __restrict__ W2,
    const float* __restrict__ WG, const float* __restrict__ WLd,
    const float* __restrict__ WLo, float* __restrict__ ws)
{
  const int tid = blockIdx.x*256 + threadIdx.x;
  const int nth = gridDim.x*256;
  unsigned short* W2FH = (unsigned short*)(ws + OFF_W2FH);
  unsigned short* W2FL = (unsigned short*)(ws + OFF_W2FL);
  for (int e = tid; e < 65536; e += nth){
    int j=e&7, l=(e>>3)&63, kb=(e>>9)&7, mt=e>>12;
    int m = mt*16+(l&15), k = kb*32+((l>>4)&3)*8+j;
    float v = W2[m*256+k];
    unsigned short h = f2b(v);
    W2FH[e]=h; W2FL[e]=f2b(v-b2f(h));
  }
  unsigned short* WEFH = (unsigned short*)(ws + OFF_WEFH);
  unsigned short* WEFL = (unsigned short*)(ws + OFF_WEFL);
  for (int e = tid; e < 81920; e += nth){
    int j=e&7, l=(e>>3)&63, kb=(e>>9)&7, mt=e>>12;
    int r = mt*16+(l&15), k = kb*32+((l>>4)&3)*8+j;
    float v = 0.f;
    if (r < 24) v = WLd[r*256+k]; else if (r < 300) v = WLo[(r-24)*256+k];
    unsigned short h = f2b(v);
    WEFH[e]=h; WEFL[e]=f2b(v-b2f(h));
  }
  unsigned short* W1H = (unsigned short*)(ws + OFF_W1H16);
  unsigned short* W1L = (unsigned short*)(ws + OFF_W1L16);
  for (int e = tid; e < 8192; e += nth){
    int j=e&7, l=(e>>3)&63, mt=e>>9;
    int m = mt*16+(l&15), k = ((l>>4)&3)*8+j;
    float v = (k < 24) ? W1[m*24+k] : 0.f;
    f2h2(v, &W1H[e], &W1L[e]);
  }
  unsigned short* W2H = (unsigned short*)(ws + OFF_W2H16);
  unsigned short* W2L = (unsigned short*)(ws + OFF_W2L16);
  for (int e = tid; e < 65536; e += nth){
    int j=e&7, l=(e>>3)&63, kb=(e>>9)&7, mt=e>>12;
    int m = mt*16+(l&15), k = kb*32+((l>>4)&3)*8+j;
    f2h2(W2[m*256+k], &W2H[e], &W2L[e]);
  }
  unsigned short* WHH = (unsigned short*)(ws + OFF_WHH16);
  unsigned short* WHL = (unsigned short*)(ws + OFF_WHL16);
  for (int e = tid; e < 86016; e += nth){
    int j=e&7, l=(e>>3)&63, kb=(e>>9)&7, mt=e>>12;
    int rr = mt*16+(l&15), k = kb*32+((l>>4)&3)*8+j;
    float v = 0.f;
    if (rr < 24) v = WLd[rr*256+k];
    else if (rr < 48) v = WG[(rr-24)*256+k];
    else if (rr < 324) v = WLo[(rr-48)*256+k];
    f2h2(v, &WHH[e], &WHL[e]);
  }
}

// ---------------- Kernel 1: MFMA forward (32 samples/block), transposed-field output ----------------
__global__ __launch_bounds__(256) void k1_fwd(
    const float* __restrict__ q, const float* __restrict__ qd_g,
    const float* __restrict__ b1, const float* __restrict__ b2,
    const float* __restrict__ bG, const float* __restrict__ bLd,
    const float* __restrict__ bLo, float* __restrict__ ws,
    float* __restrict__ out)
{
  const int s0 = blockIdx.x*32, t = threadIdx.x;
  const int w = t>>6, l = t&63, l15 = l&15, l4g = (l>>4)&3;
  unsigned* MSKT = (unsigned*)(ws + OFF_MSKT);
  float* SIGT = ws + OFF_SIGT;
  float* LDT  = ws + OFF_LDT;
  float* UT   = ws + OFF_UT;
  float* LOT  = ws + OFF_LOT;

  __shared__ __align__(16) char pool[33792];   // BQ (5120) -> BH2|BL2 (33792)
  __shared__ float qd_s[32][24];
  __shared__ float Ld_s[32][24];
  __shared__ unsigned char mb[32][64];
  unsigned short* BQH = (unsigned short*)pool;        // [32][40] f16
  unsigned short* BQL = BQH + 1280;
  unsigned short* BH2 = (unsigned short*)pool;        // [32][264] f16
  unsigned short* BL2 = BH2 + 8448;

  for (int f = t; f < 768; f += 256){
    float v = q[s0*24 + f];
    int n = f/24, k = f%24;
    f2h2(v, &BQH[n*40+k], &BQL[n*40+k]);
    ((float*)qd_s)[f] = qd_g[s0*24 + f];
  }
  { int n = t>>3, k = 24 + (t&7); BQH[n*40+k]=0; BQL[n*40+k]=0; }
  __syncthreads();

  // ---- phase A: h1 pre-acts = W1 @ qT ----
  f32x4 aH[4][2], aX[4][2];
  #pragma unroll
  for (int i=0;i<4;++i) for (int nt=0;nt<2;++nt){ aH[i][nt]=(f32x4){0,0,0,0}; aX[i][nt]=(f32x4){0,0,0,0}; }
  {
    const f16x8* WH = (const f16x8*)(ws + OFF_W1H16);
    const f16x8* WL = (const f16x8*)(ws + OFF_W1L16);
    f16x8 Af[4], Al[4], Bh[2], Bl[2];
    #pragma unroll
    for (int i=0;i<4;++i){ int mt=w+4*i; Af[i]=WH[mt*64+l]; Al[i]=WL[mt*64+l]; }
    #pragma unroll
    for (int nt=0;nt<2;++nt){
      int off=(nt*16+l15)*40 + l4g*8;
      Bh[nt]=*(const f16x8*)(BQH+off); Bl[nt]=*(const f16x8*)(BQL+off);
    }
    #pragma unroll
    for (int i=0;i<4;++i)
      #pragma unroll
      for (int nt=0;nt<2;++nt){
        aH[i][nt]=__builtin_amdgcn_mfma_f32_16x16x32_f16(Af[i],Bh[nt],aH[i][nt],0,0,0);
        aX[i][nt]=__builtin_amdgcn_mfma_f32_16x16x32_f16(Af[i],Bl[nt],aX[i][nt],0,0,0);
        aX[i][nt]=__builtin_amdgcn_mfma_f32_16x16x32_f16(Al[i],Bh[nt],aX[i][nt],0,0,0);
      }
  }
  __syncthreads();
  #pragma unroll
  for (int i=0;i<4;++i){
    int m0=(w+4*i)*16+4*l4g;
    float4 bb = *(const float4*)(b1+m0);
    #pragma unroll
    for (int nt=0;nt<2;++nt){
      int n = nt*16+l15;
      unsigned nib=0; unsigned short hs[4], ls[4];
      #pragma unroll
      for (int r=0;r<4;++r){
        float val = aH[i][nt][r] + aX[i][nt][r]*(1.f/4096.f) + ((const float*)&bb)[r];
        if (val > 0.f) nib |= 1u<<r;
        f2h2(leaky(val), &hs[r], &ls[r]);
      }
      mb[n][(m0>>2)] = (unsigned char)nib;
      *(uint2*)(BH2 + n*264 + m0) = make_uint2((unsigned)hs[0]|((unsigned)hs[1]<<16),
                                               (unsigned)hs[2]|((unsigned)hs[3]<<16));
      *(uint2*)(BL2 + n*264 + m0) = make_uint2((unsigned)ls[0]|((unsigned)ls[1]<<16),
                                               (unsigned)ls[2]|((unsigned)ls[3]<<16));
    }
  }
  __syncthreads();
  { // assemble msk1 -> MSKT (coalesced across n)
    int n = t&31, w8 = t>>5; unsigned word = 0;
    #pragma unroll
    for (int b=0;b<8;++b) word |= (unsigned)(mb[n][w8*8+b] & 0xFu) << (4*b);
    MSKT[w8*NSAMP + s0+n] = word;
  }

  // ---- phase B: h2 = W2 @ h1 ----
  #pragma unroll
  for (int i=0;i<4;++i) for (int nt=0;nt<2;++nt){ aH[i][nt]=(f32x4){0,0,0,0}; aX[i][nt]=(f32x4){0,0,0,0}; }
  {
    const f16x8* WH = (const f16x8*)(ws + OFF_W2H16);
    const f16x8* WL = (const f16x8*)(ws + OFF_W2L16);
    for (int kb=0;kb<8;++kb){
      f16x8 Af[4], Al[4], Bh[2], Bl[2];
      #pragma unroll
      for (int i=0;i<4;++i){ int mt=w+4*i; Af[i]=WH[(mt*8+kb)*64+l]; Al[i]=WL[(mt*8+kb)*64+l]; }
      #pragma unroll
      for (int nt=0;nt<2;++nt){
        int off=(nt*16+l15)*264 + kb*32 + l4g*8;
        Bh[nt]=*(const f16x8*)(BH2+off); Bl[nt]=*(const f16x8*)(BL2+off);
      }
      #pragma unroll
      for (int i=0;i<4;++i)
        #pragma unroll
        for (int nt=0;nt<2;++nt){
          aH[i][nt]=__builtin_amdgcn_mfma_f32_16x16x32_f16(Af[i],Bh[nt],aH[i][nt],0,0,0);
          aX[i][nt]=__builtin_amdgcn_mfma_f32_16x16x32_f16(Af[i],Bl[nt],aX[i][nt],0,0,0);
          aX[i][nt]=__builtin_amdgcn_mfma_f32_16x16x32_f16(Al[i],Bh[nt],aX[i][nt],0,0,0);
        }
    }
  }
  __syncthreads();
  #pragma unroll
  for (int i=0;i<4;++i){
    int m0=(w+4*i)*16+4*l4g;
    float4 bb = *(const float4*)(b2+m0);
    #pragma unroll
    for (int nt=0;nt<2;++nt){
      int n = nt*16+l15;
      unsigned nib=0; unsigned short hs[4], ls[4];
      #pragma unroll
      for (int r=0;r<4;++r){
        float val = aH[i][nt][r] + aX[i][nt][r]*(1.f/4096.f) + ((const float*)&bb)[r];
        if (val > 0.f) nib |= 1u<<r;
        f2h2(leaky(val), &hs[r], &ls[r]);
      }
      mb[n][(m0>>2)] = (unsigned char)nib;
      *(uint2*)(BH2 + n*264 + m0) = make_uint2((unsigned)hs[0]|((unsigned)hs[1]<<16),
                                               (unsigned)hs[2]|((unsigned)hs[3]<<16));
      *(uint2*)(BL2 + n*264 + m0) = make_uint2((unsigned)ls[0]|((unsigned)ls[1]<<16),
                                               (unsigned)ls[2]|((unsigned)ls[3]<<16));
    }
  }
  __syncthreads();
  { // assemble msk2 -> MSKT
    int n = t&31, w8 = t>>5; unsigned word = 0;
    #pragma unroll
    for (int b=0;b<8;++b) word |= (unsigned)(mb[n][w8*8+b] & 0xFu) << (4*b);
    MSKT[(8+w8)*NSAMP + s0+n] = word;
  }

  // ---- phase C: heads = [WLd;WG;WLo;0] @ h2 ----
  for (int pass=0; pass<2; ++pass){
    f32x4 cH[3][2], cX[3][2];
    #pragma unroll
    for (int i=0;i<3;++i) for (int nt=0;nt<2;++nt){ cH[i][nt]=(f32x4){0,0,0,0}; cX[i][nt]=(f32x4){0,0,0,0}; }
    const f16x8* WH = (const f16x8*)(ws + OFF_WHH16);
    const f16x8* WL = (const f16x8*)(ws + OFF_WHL16);
    for (int kb=0;kb<8;++kb){
      f16x8 Af[3], Al[3], Bh[2], Bl[2];
      #pragma unroll
      for (int i=0;i<3;++i){
        int mt = w + 4*(3*pass+i);
        if (mt < 21){ Af[i]=WH[(mt*8+kb)*64+l]; Al[i]=WL[(mt*8+kb)*64+l]; }
      }
      #pragma unroll
      for (int nt=0;nt<2;++nt){
        int off=(nt*16+l15)*264 + kb*32 + l4g*8;
        Bh[nt]=*(const f16x8*)(BH2+off); Bl[nt]=*(const f16x8*)(BL2+off);
      }
      #pragma unroll
      for (int i=0;i<3;++i){
        int mt = w + 4*(3*pass+i);
        if (mt < 21){
          #pragma unroll
          for (int nt=0;nt<2;++nt){
            cH[i][nt]=__builtin_amdgcn_mfma_f32_16x16x32_f16(Af[i],Bh[nt],cH[i][nt],0,0,0);
            cX[i][nt]=__builtin_amdgcn_mfma_f32_16x16x32_f16(Af[i],Bl[nt],cX[i][nt],0,0,0);
            cX[i][nt]=__builtin_amdgcn_mfma_f32_16x16x32_f16(Al[i],Bh[nt],cX[i][nt],0,0,0);
          }
        }
      }
    }
    // epilogue: transposed-field writes (coalesced across sample lanes)
    #pragma unroll
    for (int i=0;i<3;++i){
      int mt = w + 4*(3*pass+i);
      if (mt >= 21) continue;
      int m0 = mt*16+4*l4g;
      #pragma unroll
      for (int nt=0;nt<2;++nt){
        int n = nt*16+l15, sG = s0+n;
        #pragma unroll
        for (int r=0;r<4;++r){
          int rr = m0+r;
          float val = cH[i][nt][r] + cX[i][nt][r]*(1.f/4096.f);
          if (rr < 24){
            val += bLd[rr];
            SIGT[rr*NSAMP + sG] = 1.f/(1.f + expf(-val));
            float sp = fmaxf(val,0.f) + log1pf(expf(-fabsf(val)));
            LDT[rr*NSAMP + sG] = sp; Ld_s[n][rr] = sp;
          } else if (rr < 48){
            out[G_OFF + sG*24 + (rr-24)] = val + bG[rr-24];
          } else if (rr < 324){
            LOT[(rr-48)*NSAMP + sG] = val + bLo[rr-48];
          }
        }
      }
    }
  }
  __syncthreads();

  // ---- u[c] = qd[c]*Ld[c] + sum_{r>c} qd[r]*lo[r(r-1)/2+c]  (lanes span n: coalesced) ----
  {
    int n = t&31, c = t>>5;
    for (; c < 24; c += 8){
      float u = qd_s[n][c]*Ld_s[n][c];
      for (int r=c+1; r<24; ++r) u += qd_s[n][r]*LOT[(r*(r-1)/2 + c)*NSAMP + s0+n];
      UT[c*NSAMP + s0+n] = u;
    }
  }
}

// ---------------- Kernel DE: MFMA Jacobian GEMMs only (2 samples/block) ----------------
__global__ __launch_bounds__(256, 3) void kDE(
    const float* __restrict__ W1g, float* __restrict__ ws,
    float* __restrict__ Ebuf, int base)
{
  const int n0 = base + blockIdx.x*2, t = threadIdx.x;
  const int w = t >> 6, l = t & 63;
  const int l15 = l & 15, l4g = (l >> 4) & 3;
  const unsigned* MSKT = (const unsigned*)(ws + OFF_MSKT);

  __shared__ __align__(16) unsigned short BH[48*264];  // Bd then J2, bf16 hi
  __shared__ __align__(16) unsigned short BL[48*264];  // lo
  __shared__ unsigned msk[2][16];

  if (t < 32) msk[t>>4][t&15] = MSKT[(t&15)*NSAMP + n0 + (t>>4)];
  __syncthreads();

  // ---- Bd = dR1 ⊙ W1 (bf16 split), thread t owns k=t ----
  {
    float w1r[24];
    #pragma unroll
    for (int d = 0; d < 24; ++d) w1r[d] = W1g[t*24 + d];
    float dr0 = ((msk[0][t>>5] >> (t&31)) & 1u) ? 1.f : -0.01f;
    float dr1 = ((msk[1][t>>5] >> (t&31)) & 1u) ? 1.f : -0.01f;
    #pragma unroll
    for (int c = 0; c < 48; ++c){
      int s = c >= 24, d = c - 24*s;
      float f = (s ? dr1 : dr0) * w1r[d];
      unsigned short h = f2b(f);
      BH[c*264 + t] = h;
      BL[c*264 + t] = f2b(f - b2f(h));
    }
  }
  __syncthreads();

  // ---- Stage D: wave w -> M-tiles {4w..4w+3} x N-tiles {0,1,2} ----
  f32x4 accD[4][3];
  #pragma unroll
  for (int i = 0; i < 4; ++i)
    #pragma unroll
    for (int nt = 0; nt < 3; ++nt) accD[i][nt] = (f32x4){0.f,0.f,0.f,0.f};
  {
    const bf16x8* AHp = (const bf16x8*)(ws + OFF_W2FH);
    const bf16x8* ALp = (const bf16x8*)(ws + OFF_W2FL);
    for (int kb = 0; kb < 8; ++kb){
      bf16x8 AH[4], AL[4], BHf[3], BLf[3];
      #pragma unroll
      for (int i = 0; i < 4; ++i){
        int mt = 4*w + i;
        AH[i] = AHp[(mt*8+kb)*64 + l];
        AL[i] = ALp[(mt*8+kb)*64 + l];
      }
      #pragma unroll
      for (int nt = 0; nt < 3; ++nt){
        int off = (nt*16 + l15)*264 + kb*32 + l4g*8;
        BHf[nt] = *(const bf16x8*)(BH + off);
        BLf[nt] = *(const bf16x8*)(BL + off);
      }
      #pragma unroll
      for (int i = 0; i < 4; ++i)
        #pragma unroll
        for (int nt = 0; nt < 3; ++nt){
          accD[i][nt] = __builtin_amdgcn_mfma_f32_16x16x32_bf16(AH[i], BHf[nt], accD[i][nt], 0, 0, 0);
          accD[i][nt] = __builtin_amdgcn_mfma_f32_16x16x32_bf16(AH[i], BLf[nt], accD[i][nt], 0, 0, 0);
          accD[i][nt] = __builtin_amdgcn_mfma_f32_16x16x32_bf16(AL[i], BHf[nt], accD[i][nt], 0, 0, 0);
        }
    }
  }
  __syncthreads();   // all waves done reading Bd

  // ---- epilogue D: scale by dR2, re-split, store J2 over Bd ----
  #pragma unroll
  for (int i = 0; i < 4; ++i){
    int mt = 4*w + i;
    int m0 = mt*16 + 4*l4g;
    int bb = m0 & 31;
    #pragma unroll
    for (int nt = 0; nt < 3; ++nt){
      int c = nt*16 + l15;
      int s = c >= 24;
      unsigned word = msk[s][8 + (mt>>1)];
      unsigned short hs[4], ls[4];
      #pragma unroll
      for (int r = 0; r < 4; ++r){
        float sc = ((word >> (bb + r)) & 1u) ? 1.f : -0.01f;
        float v = sc * accD[i][nt][r];
        hs[r] = f2b(v); ls[r] = f2b(v - b2f(hs[r]));
      }
      *(uint2*)(BH + c*264 + m0) = make_uint2((unsigned)hs[0] | ((unsigned)hs[1]<<16),
                                              (unsigned)hs[2] | ((unsigned)hs[3]<<16));
      *(uint2*)(BL + c*264 + m0) = make_uint2((unsigned)ls[0] | ((unsigned)ls[1]<<16),
                                              (unsigned)ls[2] | ((unsigned)ls[3]<<16));
    }
  }
  __syncthreads();

  // ---- Stage E: wave w -> M-tiles {5w..5w+4} x N-tiles {0,1,2} ----
  f32x4 accE[5][3];
  #pragma unroll
  for (int i = 0; i < 5; ++i)
    #pragma unroll
    for (int nt = 0; nt < 3; ++nt) accE[i][nt] = (f32x4){0.f,0.f,0.f,0.f};
  {
    const bf16x8* AHp = (const bf16x8*)(ws + OFF_WEFH);
    const bf16x8* ALp = (const bf16x8*)(ws + OFF_WEFL);
    for (int kb = 0; kb < 8; ++kb){
      bf16x8 AH[5], AL[5], BHf[3], BLf[3];
      #pragma unroll
      for (int i = 0; i < 5; ++i){
        int mt = 5*w + i;
        AH[i] = AHp[(mt*8+kb)*64 + l];
        AL[i] = ALp[(mt*8+kb)*64 + l];
      }
      #pragma unroll
      for (int nt = 0; nt < 3; ++nt){
        int off = (nt*16 + l15)*264 + kb*32 + l4g*8;
        BHf[nt] = *(const bf16x8*)(BH + off);
        BLf[nt] = *(const bf16x8*)(BL + off);
      }
      #pragma unroll
      for (int i = 0; i < 5; ++i)
        #pragma unroll
        for (int nt = 0; nt < 3; ++nt){
          accE[i][nt] = __builtin_amdgcn_mfma_f32_16x16x32_bf16(AH[i], BHf[nt], accE[i][nt], 0, 0, 0);
          accE[i][nt] = __builtin_amdgcn_mfma_f32_16x16x32_bf16(AH[i], BLf[nt], accE[i][nt], 0, 0, 0);
          accE[i][nt] = __builtin_amdgcn_mfma_f32_16x16x32_bf16(AL[i], BHf[nt], accE[i][nt], 0, 0, 0);
        }
    }
  }

  // ---- epilogue E: raw rows -> Ebuf[(n-base)][re*24+d] ----
  #pragma unroll
  for (int i = 0; i < 5; ++i){
    int mt = 5*w + i;
    #pragma unroll
    for (int nt = 0; nt < 3; ++nt){
      int c = nt*16 + l15;
      int s = c >= 24, d = c - 24*s;
      float* eb = Ebuf + (size_t)(blockIdx.x*2 + s)*7200;
      #pragma unroll
      for (int r = 0; r < 4; ++r){
        int re = mt*16 + 4*l4g + r;
        if (re < 300) eb[re*24 + d] = accE[i][nt][r];
      }
    }
  }
}

// ---------------- Kernel T: tails (1 sample/block) ----------------
__global__ __launch_bounds__(256) void kT(
    const float* __restrict__ q_dot, const float* __restrict__ ws_c,
    const float* __restrict__ Ebuf, int base, float* __restrict__ out)
{
  const int n = base + blockIdx.x, t = threadIdx.x;
  const float* SIGT = ws_c + OFF_SIGT;
  const float* LDT  = ws_c + OFF_LDT;
  const float* UT   = ws_c + OFF_UT;
  const float* LOT  = ws_c + OFF_LOT;
  const float* eb   = Ebuf + (size_t)blockIdx.x*7200;

  __shared__ float Lp[600];            // [24][25]
  __shared__ float qp[192];            // [8][24]
  __shared__ float dt_lo[276], dt_ld[24];
  __shared__ float sig_s[24], qd_s[24], u_s[24], w1_s[24];

  if (t < 24){
    sig_s[t] = SIGT[t*NSAMP + n];
    qd_s[t]  = q_dot[n*24 + t];
    u_s[t]   = UT[t*NSAMP + n];
  }
  for (int e = t; e < 600; e += 256) Lp[e] = 0.f;
  __syncthreads();
  // L fill: diag + strict-lower (disjoint addresses; grid-stride covers all 276)
  if (t < 24) Lp[t*25 + t] = LDT[t*NSAMP + n];
  for (int p = t; p < 276; p += 256){
    int r = (int)((1.f + sqrtf(1.f + 8.f*(float)p))*0.5f);
    while (r*(r-1)/2 > p) --r;
    while ((r+1)*r/2 <= p) ++r;
    int c = p - r*(r-1)/2;
    Lp[r*25 + c] = LOT[p*NSAMP + n];
  }
  __syncthreads();

  // M = L L^T + 1e-9 I
  for (int e = t; e < 576; e += 256){
    int r = e/24, c = e%24, km = min(r,c);
    float acc = (r == c) ? 1e-9f : 0.f;
    for (int k = 0; k <= km; ++k) acc += Lp[r*25+k]*Lp[c*25+k];
    out[(size_t)n*576 + e] = acc;
  }
  // dld_dt / dlo_dt from raw E rows (grid-stride: rows 0..299)
  for (int rr = t; rr < 300; rr += 256){
    float a = 0.f;
    #pragma unroll
    for (int d = 0; d < 24; ++d) a += eb[rr*24 + d]*qd_s[d];
    if (rr < 24) dt_ld[rr] = sig_s[rr]*a; else dt_lo[rr-24] = a;
  }
  // quad partials: 8 groups x 24 rows
  if (t < 192){
    int i = t % 24, g = t / 24;
    int m = (n*24 + i) & (NSAMP-1);            // faithful cross-sample index
    const float* qdm = q_dot + m*24;
    float part = 0.f;
    for (int c2 = g; c2 < 24; c2 += 8){
      float v = qdm[c2]*sig_s[c2]*eb[c2*24 + i];
      for (int r = c2+1; r < 24; ++r)
        v += qdm[r]*eb[576 + i*276 + r*(r-1)/2 + c2];   // faithful flat reinterpretation
      part += UT[c2*NSAMP + m]*v;
    }
    qp[g*24 + i] = part;
  }
  __syncthreads();
  if (t < 24){
    int i = t;
    float a = qd_s[i]*dt_ld[i];
    for (int j = i+1; j < 24; ++j) a += qd_s[j]*dt_lo[j*(j-1)/2 + i];
    w1_s[i] = a;
  }
  __syncthreads();
  if (t < 24){
    int i = t;
    float cs = 0.f;
    for (int k = 0; k < i; ++k)
      cs += Lp[i*25+k]*w1_s[k] + dt_lo[i*(i-1)/2 + k]*u_s[k];
    cs += Lp[i*25+i]*w1_s[i] + dt_ld[i]*u_s[i];
    float quad = 0.f;
    #pragma unroll
    for (int g = 0; g < 8; ++g) quad += qp[g*24 + i];
    out[C_OFF + n*24 + i] = cs - quad;
  }
}

extern "C" void kernel_launch(void* const* d_in, const int* in_sizes, int n_in,
                              void* d_out, int out_size, void* d_ws, size_t ws_size,
                              hipStream_t stream)
{
  const float* q   = (const float*)d_in[0];
  const float* qd  = (const float*)d_in[1];
  const float* W1  = (const float*)d_in[2];
  const float* b1  = (const float*)d_in[3];
  const float* W2  = (const float*)d_in[4];
  const float* b2  = (const float*)d_in[5];
  const float* WG  = (const float*)d_in[6];
  const float* bG  = (const float*)d_in[7];
  const float* WLd = (const float*)d_in[8];
  const float* bLd = (const float*)d_in[9];
  const float* WLo = (const float*)d_in[10];
  const float* bLo = (const float*)d_in[11];
  float* out = (float*)d_out;
  float* ws  = (float*)d_ws;
  float* Ebuf = ws + OFF_EBUF;

  k0_prep<<<256, 256, 0, stream>>>(W1, W2, WG, WLd, WLo, ws);
  k1_fwd<<<NSAMP/32, 256, 0, stream>>>(q, qd, b1, b2, bG, bLd, bLo, ws, out);

  // chunk Ebuf by available workspace (deterministic given constant ws_size)
  long avail = (long)(ws_size/4) - OFF_EBUF;
  int chunk = (int)(avail / 7200);
  if (chunk > NSAMP) chunk = NSAMP;
  chunk &= ~1;
  if (chunk < 2) chunk = 2;  // assume ws is at least ~8 MB
  for (int bse = 0; bse < NSAMP; bse += chunk){
    int cur = NSAMP - bse < chunk ? NSAMP - bse : chunk;
    kDE<<<cur/2, 256, 0, stream>>>(W1, ws, Ebuf, bse);
    kT <<<cur,   256, 0, stream>>>(qd, ws, Ebuf, bse, out);
  }
}

// Round 7
// 288.331 us; speedup vs baseline: 1.2247x; 1.2247x over previous
//
#include <hip/hip_runtime.h>
#include <math.h>

#define DIM 24
#define HID 256
#define NLO 276
#define NSAMP 4096
// output layout: M [4096*576] | c [4096*24] | g [4096*24]
#define C_OFF 2359296
#define G_OFF 2457600

// workspace layout (float offsets)
#define OFF_W2FH 0          // bf16 hi, W2 MFMA-A frags (65536 sh)   32768 f
#define OFF_W2FL 32768      // bf16 lo
#define OFF_WEFH 65536      // bf16 hi, [WLd;WLo;0] frags (81920 sh) 40960 f
#define OFF_WEFL 106496
#define OFF_W1H16 147456    // f16 hi, W1 frags (8192 sh)            4096 f
#define OFF_W1L16 151552
#define OFF_W2H16 155648    // f16 hi, W2 frags (65536 sh)           32768 f
#define OFF_W2L16 188416
#define OFF_WHH16 221184    // f16 hi, heads (Ld|G|Lo|0) frags       43008 f
#define OFF_WHL16 264192
// transposed per-sample fields [field][4096]
#define OFF_MSKT 307200     // 16 u32 words x 4096
#define OFF_SIGT 372736     // 24 x 4096
#define OFF_LDT  471040     // 24 x 4096
#define OFF_UT   569344     // 24 x 4096
#define OFF_LOT  667648     // 276 x 4096

typedef __attribute__((ext_vector_type(8))) short bf16x8;
typedef __attribute__((ext_vector_type(8))) _Float16 f16x8;
typedef __attribute__((ext_vector_type(4))) float f32x4;

__device__ __forceinline__ float leaky(float x){ return x > 0.f ? x : 0.01f*x; }
__device__ __forceinline__ unsigned short f2b(float f){           // fp32 -> bf16 RNE
  unsigned u = __float_as_uint(f);
  return (unsigned short)((u + 0x7FFFu + ((u >> 16) & 1u)) >> 16);
}
__device__ __forceinline__ float b2f(unsigned short h){ return __uint_as_float(((unsigned)h) << 16); }
__device__ __forceinline__ void f2h2(float v, unsigned short* hi, unsigned short* lo){
  _Float16 h = (_Float16)v;
  _Float16 l = (_Float16)((v - (float)h) * 4096.f);
  *hi = *(unsigned short*)&h; *lo = *(unsigned short*)&l;
}

// ---------------- Kernel 0: fragment packing ----------------
__global__ __launch_bounds__(256) void k0_prep(
    const float* __restrict__ W1, const float* __restrict__ W2,
    const float* __restrict__ WG, const float* __restrict__ WLd,
    const float* __restrict__ WLo, float* __restrict__ ws)
{
  const int tid = blockIdx.x*256 + threadIdx.x;
  const int nth = gridDim.x*256;
  unsigned short* W2FH = (unsigned short*)(ws + OFF_W2FH);
  unsigned short* W2FL = (unsigned short*)(ws + OFF_W2FL);
  for (int e = tid; e < 65536; e += nth){
    int j=e&7, l=(e>>3)&63, kb=(e>>9)&7, mt=e>>12;
    int m = mt*16+(l&15), k = kb*32+((l>>4)&3)*8+j;
    float v = W2[m*256+k];
    unsigned short h = f2b(v);
    W2FH[e]=h; W2FL[e]=f2b(v-b2f(h));
  }
  unsigned short* WEFH = (unsigned short*)(ws + OFF_WEFH);
  unsigned short* WEFL = (unsigned short*)(ws + OFF_WEFL);
  for (int e = tid; e < 81920; e += nth){
    int j=e&7, l=(e>>3)&63, kb=(e>>9)&7, mt=e>>12;
    int r = mt*16+(l&15), k = kb*32+((l>>4)&3)*8+j;
    float v = 0.f;
    if (r < 24) v = WLd[r*256+k]; else if (r < 300) v = WLo[(r-24)*256+k];
    unsigned short h = f2b(v);
    WEFH[e]=h; WEFL[e]=f2b(v-b2f(h));
  }
  unsigned short* W1H = (unsigned short*)(ws + OFF_W1H16);
  unsigned short* W1L = (unsigned short*)(ws + OFF_W1L16);
  for (int e = tid; e < 8192; e += nth){
    int j=e&7, l=(e>>3)&63, mt=e>>9;
    int m = mt*16+(l&15), k = ((l>>4)&3)*8+j;
    float v = (k < 24) ? W1[m*24+k] : 0.f;
    f2h2(v, &W1H[e], &W1L[e]);
  }
  unsigned short* W2H = (unsigned short*)(ws + OFF_W2H16);
  unsigned short* W2L = (unsigned short*)(ws + OFF_W2L16);
  for (int e = tid; e < 65536; e += nth){
    int j=e&7, l=(e>>3)&63, kb=(e>>9)&7, mt=e>>12;
    int m = mt*16+(l&15), k = kb*32+((l>>4)&3)*8+j;
    f2h2(W2[m*256+k], &W2H[e], &W2L[e]);
  }
  unsigned short* WHH = (unsigned short*)(ws + OFF_WHH16);
  unsigned short* WHL = (unsigned short*)(ws + OFF_WHL16);
  for (int e = tid; e < 86016; e += nth){
    int j=e&7, l=(e>>3)&63, kb=(e>>9)&7, mt=e>>12;
    int rr = mt*16+(l&15), k = kb*32+((l>>4)&3)*8+j;
    float v = 0.f;
    if (rr < 24) v = WLd[rr*256+k];
    else if (rr < 48) v = WG[(rr-24)*256+k];
    else if (rr < 324) v = WLo[(rr-48)*256+k];
    f2h2(v, &WHH[e], &WHL[e]);
  }
}

// ---------------- Kernel 1: MFMA forward (32 samples/block), transposed-field output ----------------
__global__ __launch_bounds__(256) void k1_fwd(
    const float* __restrict__ q, const float* __restrict__ qd_g,
    const float* __restrict__ b1, const float* __restrict__ b2,
    const float* __restrict__ bG, const float* __restrict__ bLd,
    const float* __restrict__ bLo, float* __restrict__ ws,
    float* __restrict__ out)
{
  const int s0 = blockIdx.x*32, t = threadIdx.x;
  const int w = t>>6, l = t&63, l15 = l&15, l4g = (l>>4)&3;
  unsigned* MSKT = (unsigned*)(ws + OFF_MSKT);
  float* SIGT = ws + OFF_SIGT;
  float* LDT  = ws + OFF_LDT;
  float* UT   = ws + OFF_UT;
  float* LOT  = ws + OFF_LOT;

  __shared__ __align__(16) char pool[33792];   // BQ (5120) -> BH2|BL2 (33792)
  __shared__ float qd_s[32][24];
  __shared__ float Ld_s[32][24];
  __shared__ unsigned char mb[32][64];
  unsigned short* BQH = (unsigned short*)pool;        // [32][40] f16
  unsigned short* BQL = BQH + 1280;
  unsigned short* BH2 = (unsigned short*)pool;        // [32][264] f16
  unsigned short* BL2 = BH2 + 8448;

  for (int f = t; f < 768; f += 256){
    float v = q[s0*24 + f];
    int n = f/24, k = f%24;
    f2h2(v, &BQH[n*40+k], &BQL[n*40+k]);
    ((float*)qd_s)[f] = qd_g[s0*24 + f];
  }
  { int n = t>>3, k = 24 + (t&7); BQH[n*40+k]=0; BQL[n*40+k]=0; }
  __syncthreads();

  // ---- phase A: h1 pre-acts = W1 @ qT ----
  f32x4 aH[4][2], aX[4][2];
  #pragma unroll
  for (int i=0;i<4;++i) for (int nt=0;nt<2;++nt){ aH[i][nt]=(f32x4){0,0,0,0}; aX[i][nt]=(f32x4){0,0,0,0}; }
  {
    const f16x8* WH = (const f16x8*)(ws + OFF_W1H16);
    const f16x8* WL = (const f16x8*)(ws + OFF_W1L16);
    f16x8 Af[4], Al[4], Bh[2], Bl[2];
    #pragma unroll
    for (int i=0;i<4;++i){ int mt=w+4*i; Af[i]=WH[mt*64+l]; Al[i]=WL[mt*64+l]; }
    #pragma unroll
    for (int nt=0;nt<2;++nt){
      int off=(nt*16+l15)*40 + l4g*8;
      Bh[nt]=*(const f16x8*)(BQH+off); Bl[nt]=*(const f16x8*)(BQL+off);
    }
    #pragma unroll
    for (int i=0;i<4;++i)
      #pragma unroll
      for (int nt=0;nt<2;++nt){
        aH[i][nt]=__builtin_amdgcn_mfma_f32_16x16x32_f16(Af[i],Bh[nt],aH[i][nt],0,0,0);
        aX[i][nt]=__builtin_amdgcn_mfma_f32_16x16x32_f16(Af[i],Bl[nt],aX[i][nt],0,0,0);
        aX[i][nt]=__builtin_amdgcn_mfma_f32_16x16x32_f16(Al[i],Bh[nt],aX[i][nt],0,0,0);
      }
  }
  __syncthreads();
  #pragma unroll
  for (int i=0;i<4;++i){
    int m0=(w+4*i)*16+4*l4g;
    float4 bb = *(const float4*)(b1+m0);
    #pragma unroll
    for (int nt=0;nt<2;++nt){
      int n = nt*16+l15;
      unsigned nib=0; unsigned short hs[4], ls[4];
      #pragma unroll
      for (int r=0;r<4;++r){
        float val = aH[i][nt][r] + aX[i][nt][r]*(1.f/4096.f) + ((const float*)&bb)[r];
        if (val > 0.f) nib |= 1u<<r;
        f2h2(leaky(val), &hs[r], &ls[r]);
      }
      mb[n][(m0>>2)] = (unsigned char)nib;
      *(uint2*)(BH2 + n*264 + m0) = make_uint2((unsigned)hs[0]|((unsigned)hs[1]<<16),
                                               (unsigned)hs[2]|((unsigned)hs[3]<<16));
      *(uint2*)(BL2 + n*264 + m0) = make_uint2((unsigned)ls[0]|((unsigned)ls[1]<<16),
                                               (unsigned)ls[2]|((unsigned)ls[3]<<16));
    }
  }
  __syncthreads();
  { // assemble msk1 -> MSKT (coalesced across n)
    int n = t&31, w8 = t>>5; unsigned word = 0;
    #pragma unroll
    for (int b=0;b<8;++b) word |= (unsigned)(mb[n][w8*8+b] & 0xFu) << (4*b);
    MSKT[w8*NSAMP + s0+n] = word;
  }

  // ---- phase B: h2 = W2 @ h1 ----
  #pragma unroll
  for (int i=0;i<4;++i) for (int nt=0;nt<2;++nt){ aH[i][nt]=(f32x4){0,0,0,0}; aX[i][nt]=(f32x4){0,0,0,0}; }
  {
    const f16x8* WH = (const f16x8*)(ws + OFF_W2H16);
    const f16x8* WL = (const f16x8*)(ws + OFF_W2L16);
    for (int kb=0;kb<8;++kb){
      f16x8 Af[4], Al[4], Bh[2], Bl[2];
      #pragma unroll
      for (int i=0;i<4;++i){ int mt=w+4*i; Af[i]=WH[(mt*8+kb)*64+l]; Al[i]=WL[(mt*8+kb)*64+l]; }
      #pragma unroll
      for (int nt=0;nt<2;++nt){
        int off=(nt*16+l15)*264 + kb*32 + l4g*8;
        Bh[nt]=*(const f16x8*)(BH2+off); Bl[nt]=*(const f16x8*)(BL2+off);
      }
      #pragma unroll
      for (int i=0;i<4;++i)
        #pragma unroll
        for (int nt=0;nt<2;++nt){
          aH[i][nt]=__builtin_amdgcn_mfma_f32_16x16x32_f16(Af[i],Bh[nt],aH[i][nt],0,0,0);
          aX[i][nt]=__builtin_amdgcn_mfma_f32_16x16x32_f16(Af[i],Bl[nt],aX[i][nt],0,0,0);
          aX[i][nt]=__builtin_amdgcn_mfma_f32_16x16x32_f16(Al[i],Bh[nt],aX[i][nt],0,0,0);
        }
    }
  }
  __syncthreads();
  #pragma unroll
  for (int i=0;i<4;++i){
    int m0=(w+4*i)*16+4*l4g;
    float4 bb = *(const float4*)(b2+m0);
    #pragma unroll
    for (int nt=0;nt<2;++nt){
      int n = nt*16+l15;
      unsigned nib=0; unsigned short hs[4], ls[4];
      #pragma unroll
      for (int r=0;r<4;++r){
        float val = aH[i][nt][r] + aX[i][nt][r]*(1.f/4096.f) + ((const float*)&bb)[r];
        if (val > 0.f) nib |= 1u<<r;
        f2h2(leaky(val), &hs[r], &ls[r]);
      }
      mb[n][(m0>>2)] = (unsigned char)nib;
      *(uint2*)(BH2 + n*264 + m0) = make_uint2((unsigned)hs[0]|((unsigned)hs[1]<<16),
                                               (unsigned)hs[2]|((unsigned)hs[3]<<16));
      *(uint2*)(BL2 + n*264 + m0) = make_uint2((unsigned)ls[0]|((unsigned)ls[1]<<16),
                                               (unsigned)ls[2]|((unsigned)ls[3]<<16));
    }
  }
  __syncthreads();
  { // assemble msk2 -> MSKT
    int n = t&31, w8 = t>>5; unsigned word = 0;
    #pragma unroll
    for (int b=0;b<8;++b) word |= (unsigned)(mb[n][w8*8+b] & 0xFu) << (4*b);
    MSKT[(8+w8)*NSAMP + s0+n] = word;
  }

  // ---- phase C: heads = [WLd;WG;WLo;0] @ h2 ----
  for (int pass=0; pass<2; ++pass){
    f32x4 cH[3][2], cX[3][2];
    #pragma unroll
    for (int i=0;i<3;++i) for (int nt=0;nt<2;++nt){ cH[i][nt]=(f32x4){0,0,0,0}; cX[i][nt]=(f32x4){0,0,0,0}; }
    const f16x8* WH = (const f16x8*)(ws + OFF_WHH16);
    const f16x8* WL = (const f16x8*)(ws + OFF_WHL16);
    for (int kb=0;kb<8;++kb){
      f16x8 Af[3], Al[3], Bh[2], Bl[2];
      #pragma unroll
      for (int i=0;i<3;++i){
        int mt = w + 4*(3*pass+i);
        if (mt < 21){ Af[i]=WH[(mt*8+kb)*64+l]; Al[i]=WL[(mt*8+kb)*64+l]; }
      }
      #pragma unroll
      for (int nt=0;nt<2;++nt){
        int off=(nt*16+l15)*264 + kb*32 + l4g*8;
        Bh[nt]=*(const f16x8*)(BH2+off); Bl[nt]=*(const f16x8*)(BL2+off);
      }
      #pragma unroll
      for (int i=0;i<3;++i){
        int mt = w + 4*(3*pass+i);
        if (mt < 21){
          #pragma unroll
          for (int nt=0;nt<2;++nt){
            cH[i][nt]=__builtin_amdgcn_mfma_f32_16x16x32_f16(Af[i],Bh[nt],cH[i][nt],0,0,0);
            cX[i][nt]=__builtin_amdgcn_mfma_f32_16x16x32_f16(Af[i],Bl[nt],cX[i][nt],0,0,0);
            cX[i][nt]=__builtin_amdgcn_mfma_f32_16x16x32_f16(Al[i],Bh[nt],cX[i][nt],0,0,0);
          }
        }
      }
    }
    // epilogue: transposed-field writes (coalesced across sample lanes)
    #pragma unroll
    for (int i=0;i<3;++i){
      int mt = w + 4*(3*pass+i);
      if (mt >= 21) continue;
      int m0 = mt*16+4*l4g;
      #pragma unroll
      for (int nt=0;nt<2;++nt){
        int n = nt*16+l15, sG = s0+n;
        #pragma unroll
        for (int r=0;r<4;++r){
          int rr = m0+r;
          float val = cH[i][nt][r] + cX[i][nt][r]*(1.f/4096.f);
          if (rr < 24){
            val += bLd[rr];
            SIGT[rr*NSAMP + sG] = 1.f/(1.f + expf(-val));
            float sp = fmaxf(val,0.f) + log1pf(expf(-fabsf(val)));
            LDT[rr*NSAMP + sG] = sp; Ld_s[n][rr] = sp;
          } else if (rr < 48){
            out[G_OFF + sG*24 + (rr-24)] = val + bG[rr-24];
          } else if (rr < 324){
            LOT[(rr-48)*NSAMP + sG] = val + bLo[rr-48];
          }
        }
      }
    }
  }
  __syncthreads();

  // ---- u[c] = qd[c]*Ld[c] + sum_{r>c} qd[r]*lo[r(r-1)/2+c]  (lanes span n: coalesced) ----
  {
    int n = t&31, c = t>>5;
    for (; c < 24; c += 8){
      float u = qd_s[n][c]*Ld_s[n][c];
      for (int r=c+1; r<24; ++r) u += qd_s[n][r]*LOT[(r*(r-1)/2 + c)*NSAMP + s0+n];
      UT[c*NSAMP + s0+n] = u;
    }
  }
}

// ---------------- Kernel DE: MFMA Jacobian GEMMs + fused tails (2 samples/block) ----------------
__global__ __launch_bounds__(256, 3) void kDE(
    const float* __restrict__ q_dot, const float* __restrict__ W1g,
    float* __restrict__ ws, float* __restrict__ out)
{
  const int n0 = blockIdx.x*2, t = threadIdx.x;
  const int w = t >> 6, l = t & 63;
  const int l15 = l & 15, l4g = (l >> 4) & 3;
  const unsigned* MSKT = (const unsigned*)(ws + OFF_MSKT);
  const float* SIGT = ws + OFF_SIGT;
  const float* LDT  = ws + OFF_LDT;
  const float* UT   = ws + OFF_UT;
  const float* LOT  = ws + OFF_LOT;

  // pool: [BH|BL] bf16 (50688 B) during GEMMs; tail overlay (~34.8 KB) after
  __shared__ __align__(16) char pool[50688];
  __shared__ unsigned msk[2][16];
  unsigned short* BH = (unsigned short*)pool;
  unsigned short* BL = BH + 12672;
  // tail overlay
  float* Ef   = (float*)pool;            // [300][25] raw E rows (30000 B)
  float* Lp   = (float*)(pool + 30000);  // [24][25]
  float* dtlo = (float*)(pool + 32400);  // [276]
  float* dtld = (float*)(pool + 33504);  // [24]
  float* w1s  = (float*)(pool + 33600);  // [24]
  float* qps  = (float*)(pool + 33696);  // [8][24]
  float* sigs = (float*)(pool + 34464);  // [24]
  float* qds  = (float*)(pool + 34560);  // [24]
  float* uss  = (float*)(pool + 34656);  // [24]

  if (t < 32) msk[t>>4][t&15] = MSKT[(t&15)*NSAMP + n0 + (t>>4)];
  __syncthreads();

  // ---- Bd = dR1 ⊙ W1 (bf16 split), thread t owns k=t ----
  {
    float w1r[24];
    #pragma unroll
    for (int d = 0; d < 24; ++d) w1r[d] = W1g[t*24 + d];
    float dr0 = ((msk[0][t>>5] >> (t&31)) & 1u) ? 1.f : -0.01f;
    float dr1 = ((msk[1][t>>5] >> (t&31)) & 1u) ? 1.f : -0.01f;
    #pragma unroll
    for (int c = 0; c < 48; ++c){
      int s = c >= 24, d = c - 24*s;
      float f = (s ? dr1 : dr0) * w1r[d];
      unsigned short h = f2b(f);
      BH[c*264 + t] = h;
      BL[c*264 + t] = f2b(f - b2f(h));
    }
  }
  __syncthreads();

  // ---- Stage D: wave w -> M-tiles {4w..4w+3} x N-tiles {0,1,2} ----
  f32x4 accD[4][3];
  #pragma unroll
  for (int i = 0; i < 4; ++i)
    #pragma unroll
    for (int nt = 0; nt < 3; ++nt) accD[i][nt] = (f32x4){0.f,0.f,0.f,0.f};
  {
    const bf16x8* AHp = (const bf16x8*)(ws + OFF_W2FH);
    const bf16x8* ALp = (const bf16x8*)(ws + OFF_W2FL);
    for (int kb = 0; kb < 8; ++kb){
      bf16x8 AH[4], AL[4], BHf[3], BLf[3];
      #pragma unroll
      for (int i = 0; i < 4; ++i){
        int mt = 4*w + i;
        AH[i] = AHp[(mt*8+kb)*64 + l];
        AL[i] = ALp[(mt*8+kb)*64 + l];
      }
      #pragma unroll
      for (int nt = 0; nt < 3; ++nt){
        int off = (nt*16 + l15)*264 + kb*32 + l4g*8;
        BHf[nt] = *(const bf16x8*)(BH + off);
        BLf[nt] = *(const bf16x8*)(BL + off);
      }
      #pragma unroll
      for (int i = 0; i < 4; ++i)
        #pragma unroll
        for (int nt = 0; nt < 3; ++nt){
          accD[i][nt] = __builtin_amdgcn_mfma_f32_16x16x32_bf16(AH[i], BHf[nt], accD[i][nt], 0, 0, 0);
          accD[i][nt] = __builtin_amdgcn_mfma_f32_16x16x32_bf16(AH[i], BLf[nt], accD[i][nt], 0, 0, 0);
          accD[i][nt] = __builtin_amdgcn_mfma_f32_16x16x32_bf16(AL[i], BHf[nt], accD[i][nt], 0, 0, 0);
        }
    }
  }
  __syncthreads();   // all waves done reading Bd

  // ---- epilogue D: scale by dR2, re-split, store J2 over Bd ----
  #pragma unroll
  for (int i = 0; i < 4; ++i){
    int mt = 4*w + i;
    int m0 = mt*16 + 4*l4g;
    int bb = m0 & 31;
    #pragma unroll
    for (int nt = 0; nt < 3; ++nt){
      int c = nt*16 + l15;
      int s = c >= 24;
      unsigned word = msk[s][8 + (mt>>1)];
      unsigned short hs[4], ls[4];
      #pragma unroll
      for (int r = 0; r < 4; ++r){
        float sc = ((word >> (bb + r)) & 1u) ? 1.f : -0.01f;
        float v = sc * accD[i][nt][r];
        hs[r] = f2b(v); ls[r] = f2b(v - b2f(hs[r]));
      }
      *(uint2*)(BH + c*264 + m0) = make_uint2((unsigned)hs[0] | ((unsigned)hs[1]<<16),
                                              (unsigned)hs[2] | ((unsigned)hs[3]<<16));
      *(uint2*)(BL + c*264 + m0) = make_uint2((unsigned)ls[0] | ((unsigned)ls[1]<<16),
                                              (unsigned)ls[2] | ((unsigned)ls[3]<<16));
    }
  }
  __syncthreads();

  // ---- Stage E: wave w -> M-tiles {5w..5w+4} x N-tiles {0,1,2} ----
  f32x4 accE[5][3];
  #pragma unroll
  for (int i = 0; i < 5; ++i)
    #pragma unroll
    for (int nt = 0; nt < 3; ++nt) accE[i][nt] = (f32x4){0.f,0.f,0.f,0.f};
  {
    const bf16x8* AHp = (const bf16x8*)(ws + OFF_WEFH);
    const bf16x8* ALp = (const bf16x8*)(ws + OFF_WEFL);
    for (int kb = 0; kb < 8; ++kb){
      bf16x8 AH[5], AL[5], BHf[3], BLf[3];
      #pragma unroll
      for (int i = 0; i < 5; ++i){
        int mt = 5*w + i;
        AH[i] = AHp[(mt*8+kb)*64 + l];
        AL[i] = ALp[(mt*8+kb)*64 + l];
      }
      #pragma unroll
      for (int nt = 0; nt < 3; ++nt){
        int off = (nt*16 + l15)*264 + kb*32 + l4g*8;
        BHf[nt] = *(const bf16x8*)(BH + off);
        BLf[nt] = *(const bf16x8*)(BL + off);
      }
      #pragma unroll
      for (int i = 0; i < 5; ++i)
        #pragma unroll
        for (int nt = 0; nt < 3; ++nt){
          accE[i][nt] = __builtin_amdgcn_mfma_f32_16x16x32_bf16(AH[i], BHf[nt], accE[i][nt], 0, 0, 0);
          accE[i][nt] = __builtin_amdgcn_mfma_f32_16x16x32_bf16(AH[i], BLf[nt], accE[i][nt], 0, 0, 0);
          accE[i][nt] = __builtin_amdgcn_mfma_f32_16x16x32_bf16(AL[i], BHf[nt], accE[i][nt], 0, 0, 0);
        }
    }
  }
  __syncthreads();   // all waves done reading J2 -> pool is free for tail overlay

  // ---- fused tails, sample-sequential (accE for the other sample stays in regs) ----
  for (int s = 0; s < 2; ++s){
    const int n = n0 + s;
    // scatter raw E cols of sample s into Ef (stride 25, conflict-free)
    #pragma unroll
    for (int i = 0; i < 5; ++i){
      int mt = 5*w + i;
      #pragma unroll
      for (int nt = 0; nt < 3; ++nt){
        int c = nt*16 + l15;
        if ((c >= 24) == (s == 1)){
          int d = c - 24*s;
          #pragma unroll
          for (int r = 0; r < 4; ++r){
            int re = mt*16 + 4*l4g + r;
            if (re < 300) Ef[re*25 + d] = accE[i][nt][r];
          }
        }
      }
    }
    if (t < 24){
      sigs[t] = SIGT[t*NSAMP + n];
      qds[t]  = q_dot[n*24 + t];
      uss[t]  = UT[t*NSAMP + n];
      Lp[t*25 + t] = LDT[t*NSAMP + n];
    }
    for (int p = t; p < 276; p += 256){     // strict-lower L fill (tri decode)
      int r = (int)((1.f + sqrtf(1.f + 8.f*(float)p))*0.5f);
      while (r*(r-1)/2 > p) --r;
      while ((r+1)*r/2 <= p) ++r;
      int cc = p - r*(r-1)/2;
      Lp[r*25 + cc] = LOT[p*NSAMP + n];
    }
    __syncthreads();

    // M = L L^T + 1e-9 I  (only lower+diag of Lp is read)
    for (int e = t; e < 576; e += 256){
      int r = e/24, cc = e%24, km = min(r,cc);
      float acc = (r == cc) ? 1e-9f : 0.f;
      for (int k = 0; k <= km; ++k) acc += Lp[r*25+k]*Lp[cc*25+k];
      out[(size_t)n*576 + e] = acc;
    }
    // dld_dt / dlo_dt from raw E rows
    for (int rr = t; rr < 300; rr += 256){
      float a = 0.f;
      #pragma unroll
      for (int d = 0; d < 24; ++d) a += Ef[rr*25 + d]*qds[d];
      if (rr < 24) dtld[rr] = sigs[rr]*a; else dtlo[rr-24] = a;
    }
    __syncthreads();

    // quad partials (t<192) || w1 (t in [192,216))
    if (t < 192){
      int i = t % 24, g = t / 24;
      int m = (n*24 + i) & (NSAMP-1);              // faithful cross-sample index
      float qr[24];
      const float4* q4 = (const float4*)(q_dot + m*24);
      #pragma unroll
      for (int v4 = 0; v4 < 6; ++v4){
        float4 x = q4[v4];
        qr[4*v4+0]=x.x; qr[4*v4+1]=x.y; qr[4*v4+2]=x.z; qr[4*v4+3]=x.w;
      }
      float part = 0.f;
      for (int c2 = g; c2 < 24; c2 += 8){
        float v = qr[c2]*sigs[c2]*Ef[c2*25 + i];
        for (int r = c2+1; r < 24; ++r){
          int f = i*276 + r*(r-1)/2 + c2;          // faithful flat reinterpretation
          v += qr[r]*Ef[(24 + f/24)*25 + (f%24)];
        }
        part += UT[c2*NSAMP + m]*v;
      }
      qps[g*24 + i] = part;
    } else if (t < 216){
      int i = t - 192;
      float a = qds[i]*dtld[i];
      for (int j = i+1; j < 24; ++j) a += qds[j]*dtlo[j*(j-1)/2 + i];
      w1s[i] = a;
    }
    __syncthreads();

    if (t < 24){
      int i = t;
      float cs = 0.f;
      for (int k = 0; k < i; ++k)
        cs += Lp[i*25+k]*w1s[k] + dtlo[i*(i-1)/2 + k]*uss[k];
      cs += Lp[i*25+i]*w1s[i] + dtld[i]*uss[i];
      float quad = 0.f;
      #pragma unroll
      for (int g = 0; g < 8; ++g) quad += qps[g*24 + i];
      out[C_OFF + n*24 + i] = cs - quad;
    }
    __syncthreads();   // before next sample overwrites the overlay
  }
}

extern "C" void kernel_launch(void* const* d_in, const int* in_sizes, int n_in,
                              void* d_out, int out_size, void* d_ws, size_t ws_size,
                              hipStream_t stream)
{
  const float* q   = (const float*)d_in[0];
  const float* qd  = (const float*)d_in[1];
  const float* W1  = (const float*)d_in[2];
  const float* b1  = (const float*)d_in[3];
  const float* W2  = (const float*)d_in[4];
  const float* b2  = (const float*)d_in[5];
  const float* WG  = (const float*)d_in[6];
  const float* bG  = (const float*)d_in[7];
  const float* WLd = (const float*)d_in[8];
  const float* bLd = (const float*)d_in[9];
  const float* WLo = (const float*)d_in[10];
  const float* bLo = (const float*)d_in[11];
  float* out = (float*)d_out;
  float* ws  = (float*)d_ws;

  k0_prep<<<256, 256, 0, stream>>>(W1, W2, WG, WLd, WLo, ws);
  k1_fwd<<<NSAMP/32, 256, 0, stream>>>(q, qd, b1, b2, bG, bLd, bLo, ws, out);
  kDE<<<NSAMP/2, 256, 0, stream>>>(qd, W1, ws, out);
}

// Round 9
// 266.300 us; speedup vs baseline: 1.3260x; 1.0827x over previous
//
#include <hip/hip_runtime.h>
#include <math.h>

#define DIM 24
#define HID 256
#define NLO 276
#define NSAMP 4096
// output layout: M [4096*576] | c [4096*24] | g [4096*24]
#define C_OFF 2359296
#define G_OFF 2457600

// workspace layout (float offsets)
#define OFF_W2FH 0          // bf16 hi, W2 MFMA-A frags (65536 sh)   32768 f
#define OFF_W2FL 32768      // bf16 lo
#define OFF_WEFH 65536      // bf16 hi, [WLd;WLo;0] frags (81920 sh) 40960 f
#define OFF_WEFL 106496
#define OFF_W1H16 147456    // f16 hi, W1 frags (8192 sh)            4096 f
#define OFF_W1L16 151552
#define OFF_W2H16 155648    // f16 hi, W2 frags (65536 sh)           32768 f
#define OFF_W2L16 188416
#define OFF_WHH16 221184    // f16 hi, heads (Ld|G|Lo|0) frags       43008 f
#define OFF_WHL16 264192
// transposed per-sample fields [field][4096]
#define OFF_MSKT 307200     // 16 u32 words x 4096
#define OFF_SIGT 372736     // 24 x 4096
#define OFF_LDT  471040     // 24 x 4096
#define OFF_UT   569344     // 24 x 4096
#define OFF_LOT  667648     // 276 x 4096

typedef __attribute__((ext_vector_type(8))) short bf16x8;
typedef __attribute__((ext_vector_type(8))) _Float16 f16x8;
typedef __attribute__((ext_vector_type(4))) float f32x4;

__device__ __forceinline__ float leaky(float x){ return x > 0.f ? x : 0.01f*x; }
__device__ __forceinline__ unsigned short f2b(float f){           // fp32 -> bf16 RNE
  unsigned u = __float_as_uint(f);
  return (unsigned short)((u + 0x7FFFu + ((u >> 16) & 1u)) >> 16);
}
__device__ __forceinline__ float b2f(unsigned short h){ return __uint_as_float(((unsigned)h) << 16); }
__device__ __forceinline__ void f2h2(float v, unsigned short* hi, unsigned short* lo){
  _Float16 h = (_Float16)v;
  _Float16 l = (_Float16)((v - (float)h) * 4096.f);
  *hi = *(unsigned short*)&h; *lo = *(unsigned short*)&l;
}

// ---------------- Kernel 0: fragment packing ----------------
__global__ __launch_bounds__(256) void k0_prep(
    const float* __restrict__ W1, const float* __restrict__ W2,
    const float* __restrict__ WG, const float* __restrict__ WLd,
    const float* __restrict__ WLo, float* __restrict__ ws)
{
  const int tid = blockIdx.x*256 + threadIdx.x;
  const int nth = gridDim.x*256;
  unsigned short* W2FH = (unsigned short*)(ws + OFF_W2FH);
  unsigned short* W2FL = (unsigned short*)(ws + OFF_W2FL);
  for (int e = tid; e < 65536; e += nth){
    int j=e&7, l=(e>>3)&63, kb=(e>>9)&7, mt=e>>12;
    int m = mt*16+(l&15), k = kb*32+((l>>4)&3)*8+j;
    float v = W2[m*256+k];
    unsigned short h = f2b(v);
    W2FH[e]=h; W2FL[e]=f2b(v-b2f(h));
  }
  unsigned short* WEFH = (unsigned short*)(ws + OFF_WEFH);
  unsigned short* WEFL = (unsigned short*)(ws + OFF_WEFL);
  for (int e = tid; e < 81920; e += nth){
    int j=e&7, l=(e>>3)&63, kb=(e>>9)&7, mt=e>>12;
    int r = mt*16+(l&15), k = kb*32+((l>>4)&3)*8+j;
    float v = 0.f;
    if (r < 24) v = WLd[r*256+k]; else if (r < 300) v = WLo[(r-24)*256+k];
    unsigned short h = f2b(v);
    WEFH[e]=h; WEFL[e]=f2b(v-b2f(h));
  }
  unsigned short* W1H = (unsigned short*)(ws + OFF_W1H16);
  unsigned short* W1L = (unsigned short*)(ws + OFF_W1L16);
  for (int e = tid; e < 8192; e += nth){
    int j=e&7, l=(e>>3)&63, mt=e>>9;
    int m = mt*16+(l&15), k = ((l>>4)&3)*8+j;
    float v = (k < 24) ? W1[m*24+k] : 0.f;
    f2h2(v, &W1H[e], &W1L[e]);
  }
  unsigned short* W2H = (unsigned short*)(ws + OFF_W2H16);
  unsigned short* W2L = (unsigned short*)(ws + OFF_W2L16);
  for (int e = tid; e < 65536; e += nth){
    int j=e&7, l=(e>>3)&63, kb=(e>>9)&7, mt=e>>12;
    int m = mt*16+(l&15), k = kb*32+((l>>4)&3)*8+j;
    f2h2(W2[m*256+k], &W2H[e], &W2L[e]);
  }
  unsigned short* WHH = (unsigned short*)(ws + OFF_WHH16);
  unsigned short* WHL = (unsigned short*)(ws + OFF_WHL16);
  for (int e = tid; e < 86016; e += nth){
    int j=e&7, l=(e>>3)&63, kb=(e>>9)&7, mt=e>>12;
    int rr = mt*16+(l&15), k = kb*32+((l>>4)&3)*8+j;
    float v = 0.f;
    if (rr < 24) v = WLd[rr*256+k];
    else if (rr < 48) v = WG[(rr-24)*256+k];
    else if (rr < 324) v = WLo[(rr-48)*256+k];
    f2h2(v, &WHH[e], &WHL[e]);
  }
}

// ---------------- Kernel 1: MFMA forward (8 samples/block, 512 blocks) ----------------
__global__ __launch_bounds__(256) void k1_fwd(
    const float* __restrict__ q,
    const float* __restrict__ b1, const float* __restrict__ b2,
    const float* __restrict__ bG, const float* __restrict__ bLd,
    const float* __restrict__ bLo, float* __restrict__ ws,
    float* __restrict__ out)
{
  const int s0 = blockIdx.x*8, t = threadIdx.x;
  const int w = t>>6, l = t&63, l15 = l&15, l4g = (l>>4)&3;
  unsigned* MSKT = (unsigned*)(ws + OFF_MSKT);
  float* SIGT = ws + OFF_SIGT;
  float* LDT  = ws + OFF_LDT;
  float* LOT  = ws + OFF_LOT;

  __shared__ __align__(16) unsigned short pool[8448];  // BQ (640 sh) -> BH2|BL2 (8448 sh)
  __shared__ unsigned char mb[8][64];
  unsigned short* BQH = pool;            // [8][40] f16
  unsigned short* BQL = BQH + 320;
  unsigned short* BH2 = pool;            // [8][264] f16
  unsigned short* BL2 = BH2 + 2112;

  for (int f = t; f < 192; f += 256){
    float v = q[s0*24 + f];
    int n = f/24, k = f%24;
    f2h2(v, &BQH[n*40+k], &BQL[n*40+k]);
  }
  if (t < 64){ int n = t>>3, k = 24 + (t&7); BQH[n*40+k]=0; BQL[n*40+k]=0; }
  __syncthreads();

  // ---- phase A: h1 pre-acts = W1 @ qT (cols 8..15 garbage, never stored) ----
  f32x4 aH[4], aX[4];
  #pragma unroll
  for (int i=0;i<4;++i){ aH[i]=(f32x4){0,0,0,0}; aX[i]=(f32x4){0,0,0,0}; }
  {
    const f16x8* WH = (const f16x8*)(ws + OFF_W1H16);
    const f16x8* WL = (const f16x8*)(ws + OFF_W1L16);
    f16x8 Af[4], Al[4];
    #pragma unroll
    for (int i=0;i<4;++i){ int mt=w+4*i; Af[i]=WH[mt*64+l]; Al[i]=WL[mt*64+l]; }
    int off = l15*40 + l4g*8;
    f16x8 Bh = *(const f16x8*)(BQH+off), Bl = *(const f16x8*)(BQL+off);
    #pragma unroll
    for (int i=0;i<4;++i){
      aH[i]=__builtin_amdgcn_mfma_f32_16x16x32_f16(Af[i],Bh,aH[i],0,0,0);
      aX[i]=__builtin_amdgcn_mfma_f32_16x16x32_f16(Af[i],Bl,aX[i],0,0,0);
      aX[i]=__builtin_amdgcn_mfma_f32_16x16x32_f16(Al[i],Bh,aX[i],0,0,0);
    }
  }
  __syncthreads();
  #pragma unroll
  for (int i=0;i<4;++i){
    int m0=(w+4*i)*16+4*l4g;
    float4 bb = *(const float4*)(b1+m0);
    int n = l15;
    if (n < 8){
      unsigned nib=0; unsigned short hs[4], ls[4];
      #pragma unroll
      for (int r=0;r<4;++r){
        float val = aH[i][r] + aX[i][r]*(1.f/4096.f) + ((const float*)&bb)[r];
        if (val > 0.f) nib |= 1u<<r;
        f2h2(leaky(val), &hs[r], &ls[r]);
      }
      mb[n][(m0>>2)] = (unsigned char)nib;
      *(uint2*)(BH2 + n*264 + m0) = make_uint2((unsigned)hs[0]|((unsigned)hs[1]<<16),
                                               (unsigned)hs[2]|((unsigned)hs[3]<<16));
      *(uint2*)(BL2 + n*264 + m0) = make_uint2((unsigned)ls[0]|((unsigned)ls[1]<<16),
                                               (unsigned)ls[2]|((unsigned)ls[3]<<16));
    }
  }
  __syncthreads();
  if (t < 64){ // msk1 -> MSKT
    int n = t&7, w8 = t>>3; unsigned word = 0;
    #pragma unroll
    for (int b=0;b<8;++b) word |= (unsigned)(mb[n][w8*8+b] & 0xFu) << (4*b);
    MSKT[w8*NSAMP + s0+n] = word;
  }

  // ---- phase B: h2 = W2 @ h1 ----
  #pragma unroll
  for (int i=0;i<4;++i){ aH[i]=(f32x4){0,0,0,0}; aX[i]=(f32x4){0,0,0,0}; }
  {
    const f16x8* WH = (const f16x8*)(ws + OFF_W2H16);
    const f16x8* WL = (const f16x8*)(ws + OFF_W2L16);
    for (int kb=0;kb<8;++kb){
      f16x8 Af[4], Al[4];
      #pragma unroll
      for (int i=0;i<4;++i){ int mt=w+4*i; Af[i]=WH[(mt*8+kb)*64+l]; Al[i]=WL[(mt*8+kb)*64+l]; }
      int off = l15*264 + kb*32 + l4g*8;
      f16x8 Bh = *(const f16x8*)(BH2+off), Bl = *(const f16x8*)(BL2+off);
      #pragma unroll
      for (int i=0;i<4;++i){
        aH[i]=__builtin_amdgcn_mfma_f32_16x16x32_f16(Af[i],Bh,aH[i],0,0,0);
        aX[i]=__builtin_amdgcn_mfma_f32_16x16x32_f16(Af[i],Bl,aX[i],0,0,0);
        aX[i]=__builtin_amdgcn_mfma_f32_16x16x32_f16(Al[i],Bh,aX[i],0,0,0);
      }
    }
  }
  __syncthreads();
  #pragma unroll
  for (int i=0;i<4;++i){
    int m0=(w+4*i)*16+4*l4g;
    float4 bb = *(const float4*)(b2+m0);
    int n = l15;
    if (n < 8){
      unsigned nib=0; unsigned short hs[4], ls[4];
      #pragma unroll
      for (int r=0;r<4;++r){
        float val = aH[i][r] + aX[i][r]*(1.f/4096.f) + ((const float*)&bb)[r];
        if (val > 0.f) nib |= 1u<<r;
        f2h2(leaky(val), &hs[r], &ls[r]);
      }
      mb[n][(m0>>2)] = (unsigned char)nib;
      *(uint2*)(BH2 + n*264 + m0) = make_uint2((unsigned)hs[0]|((unsigned)hs[1]<<16),
                                               (unsigned)hs[2]|((unsigned)hs[3]<<16));
      *(uint2*)(BL2 + n*264 + m0) = make_uint2((unsigned)ls[0]|((unsigned)ls[1]<<16),
                                               (unsigned)ls[2]|((unsigned)ls[3]<<16));
    }
  }
  __syncthreads();
  if (t < 64){ // msk2 -> MSKT
    int n = t&7, w8 = t>>3; unsigned word = 0;
    #pragma unroll
    for (int b=0;b<8;++b) word |= (unsigned)(mb[n][w8*8+b] & 0xFu) << (4*b);
    MSKT[(8+w8)*NSAMP + s0+n] = word;
  }

  // ---- phase C: heads = [WLd;WG;WLo;0] @ h2 ----
  for (int pass=0; pass<2; ++pass){
    f32x4 cH[3], cX[3];
    #pragma unroll
    for (int i=0;i<3;++i){ cH[i]=(f32x4){0,0,0,0}; cX[i]=(f32x4){0,0,0,0}; }
    const f16x8* WH = (const f16x8*)(ws + OFF_WHH16);
    const f16x8* WL = (const f16x8*)(ws + OFF_WHL16);
    for (int kb=0;kb<8;++kb){
      f16x8 Af[3], Al[3];
      #pragma unroll
      for (int i=0;i<3;++i){
        int mt = w + 4*(3*pass+i);
        if (mt < 21){ Af[i]=WH[(mt*8+kb)*64+l]; Al[i]=WL[(mt*8+kb)*64+l]; }
      }
      int off = l15*264 + kb*32 + l4g*8;
      f16x8 Bh = *(const f16x8*)(BH2+off), Bl = *(const f16x8*)(BL2+off);
      #pragma unroll
      for (int i=0;i<3;++i){
        int mt = w + 4*(3*pass+i);
        if (mt < 21){
          cH[i]=__builtin_amdgcn_mfma_f32_16x16x32_f16(Af[i],Bh,cH[i],0,0,0);
          cX[i]=__builtin_amdgcn_mfma_f32_16x16x32_f16(Af[i],Bl,cX[i],0,0,0);
          cX[i]=__builtin_amdgcn_mfma_f32_16x16x32_f16(Al[i],Bh,cX[i],0,0,0);
        }
      }
    }
    #pragma unroll
    for (int i=0;i<3;++i){
      int mt = w + 4*(3*pass+i);
      if (mt >= 21) continue;
      int m0 = mt*16+4*l4g;
      int n = l15;
      if (n < 8){
        int sG = s0+n;
        #pragma unroll
        for (int r=0;r<4;++r){
          int rr = m0+r;
          float val = cH[i][r] + cX[i][r]*(1.f/4096.f);
          if (rr < 24){
            val += bLd[rr];
            SIGT[rr*NSAMP + sG] = 1.f/(1.f + expf(-val));
            LDT[rr*NSAMP + sG] = fmaxf(val,0.f) + log1pf(expf(-fabsf(val)));
          } else if (rr < 48){
            out[G_OFF + sG*24 + (rr-24)] = val + bG[rr-24];
          } else if (rr < 324){
            LOT[(rr-48)*NSAMP + sG] = val + bLo[rr-48];
          }
        }
      }
    }
  }
}

// ---------------- Kernel U: u = L^T qd (transposed fields, fully coalesced) ----------------
__global__ __launch_bounds__(256) void kU(
    const float* __restrict__ qd_g, const float* __restrict__ ws_c,
    float* __restrict__ UT)
{
  const int t = threadIdx.x, nb = blockIdx.x*256;
  const float* LDT = ws_c + OFF_LDT;
  const float* LOT = ws_c + OFF_LOT;
  __shared__ float qd_ss[256*25];
  for (int f = t; f < 6144; f += 256){
    int nl = f/24, r = f%24;
    qd_ss[nl*25 + r] = qd_g[nb*24 + f];
  }
  __syncthreads();
  const int n = nb + t;
  #pragma unroll
  for (int c = 0; c < 24; ++c){
    float u = qd_ss[t*25+c]*LDT[c*NSAMP + n];
    for (int r = c+1; r < 24; ++r)
      u += qd_ss[t*25+r]*LOT[(r*(r-1)/2 + c)*NSAMP + n];
    UT[c*NSAMP + n] = u;
  }
}

// ---------------- Kernel M: M = L L^T + 1e-9 I (1 sample/block, high occupancy) ----------------
__global__ __launch_bounds__(256) void kM(
    const float* __restrict__ ws_c, float* __restrict__ out)
{
  const int n = blockIdx.x, t = threadIdx.x;
  const float* LDT = ws_c + OFF_LDT;
  const float* LOT = ws_c + OFF_LOT;
  __shared__ float Lp[600];
  for (int e = t; e < 600; e += 256) Lp[e] = 0.f;
  __syncthreads();
  if (t < 24) Lp[t*25 + t] = LDT[t*NSAMP + n];
  for (int p = t; p < 276; p += 256){
    int r = (int)((1.f + sqrtf(1.f + 8.f*(float)p))*0.5f);
    while (r*(r-1)/2 > p) --r;
    while ((r+1)*r/2 <= p) ++r;
    int c = p - r*(r-1)/2;
    Lp[r*25 + c] = LOT[p*NSAMP + n];
  }
  __syncthreads();
  for (int e = t; e < 576; e += 256){
    int r = e/24, c = e%24, km = min(r,c);
    float acc = (r == c) ? 1e-9f : 0.f;
    for (int k = 0; k <= km; ++k) acc += Lp[r*25+k]*Lp[c*25+k];
    out[(size_t)n*576 + e] = acc;
  }
}

// ---------------- Kernel DE: MFMA Jacobian GEMMs + lean tails (2 samples/block) ----------------
__global__ __launch_bounds__(256, 3) void kDE(
    const float* __restrict__ q_dot, const float* __restrict__ W1g,
    float* __restrict__ ws, float* __restrict__ out)
{
  const int n0 = blockIdx.x*2, t = threadIdx.x;
  const int w = t >> 6, l = t & 63;
  const int l15 = l & 15, l4g = (l >> 4) & 3;
  const unsigned* MSKT = (const unsigned*)(ws + OFF_MSKT);
  const float* SIGT = ws + OFF_SIGT;
  const float* LDT  = ws + OFF_LDT;
  const float* UT   = ws + OFF_UT;
  const float* LOT  = ws + OFF_LOT;

  // pool: [BH|BL] bf16 (50688 B) during GEMMs; tail overlay (~42 KB) after
  __shared__ __align__(16) char pool[50688];
  __shared__ unsigned msk[2][16];
  unsigned short* BH = (unsigned short*)pool;
  unsigned short* BL = BH + 12672;
  // tail overlay
  float* dlo_flat = (float*)pool;            // [276*24] flat (faithful view) 26496 B
  float* dld25    = (float*)(pool + 26496);  // [24][25]
  float* qdm_s    = (float*)(pool + 28896);  // [24][25]  q_dot rows for m_i
  float* um_s     = (float*)(pool + 31296);  // [24][25]  um_s[c][i] = UT[c][m_i]
  float* qp2      = (float*)(pool + 33696);  // [1656] dt partials
  float* dtlo     = (float*)(pool + 40320);  // [276]
  float* dtld     = (float*)(pool + 41424);  // [24]
  float* w1s      = (float*)(pool + 41520);  // [24]
  float* sigs     = (float*)(pool + 41616);  // [24]
  float* qds      = (float*)(pool + 41712);  // [24]
  float* uss      = (float*)(pool + 41808);  // [24]

  if (t < 32) msk[t>>4][t&15] = MSKT[(t&15)*NSAMP + n0 + (t>>4)];
  __syncthreads();

  // ---- Bd = dR1 ⊙ W1 (bf16 split), thread t owns k=t ----
  {
    float w1r[24];
    #pragma unroll
    for (int d = 0; d < 24; ++d) w1r[d] = W1g[t*24 + d];
    float dr0 = ((msk[0][t>>5] >> (t&31)) & 1u) ? 1.f : -0.01f;
    float dr1 = ((msk[1][t>>5] >> (t&31)) & 1u) ? 1.f : -0.01f;
    #pragma unroll
    for (int c = 0; c < 48; ++c){
      int s = c >= 24, d = c - 24*s;
      float f = (s ? dr1 : dr0) * w1r[d];
      unsigned short h = f2b(f);
      BH[c*264 + t] = h;
      BL[c*264 + t] = f2b(f - b2f(h));
    }
  }
  __syncthreads();

  // ---- Stage D ----
  f32x4 accD[4][3];
  #pragma unroll
  for (int i = 0; i < 4; ++i)
    #pragma unroll
    for (int nt = 0; nt < 3; ++nt) accD[i][nt] = (f32x4){0.f,0.f,0.f,0.f};
  {
    const bf16x8* AHp = (const bf16x8*)(ws + OFF_W2FH);
    const bf16x8* ALp = (const bf16x8*)(ws + OFF_W2FL);
    for (int kb = 0; kb < 8; ++kb){
      bf16x8 AH[4], AL[4], BHf[3], BLf[3];
      #pragma unroll
      for (int i = 0; i < 4; ++i){
        int mt = 4*w + i;
        AH[i] = AHp[(mt*8+kb)*64 + l];
        AL[i] = ALp[(mt*8+kb)*64 + l];
      }
      #pragma unroll
      for (int nt = 0; nt < 3; ++nt){
        int off = (nt*16 + l15)*264 + kb*32 + l4g*8;
        BHf[nt] = *(const bf16x8*)(BH + off);
        BLf[nt] = *(const bf16x8*)(BL + off);
      }
      #pragma unroll
      for (int i = 0; i < 4; ++i)
        #pragma unroll
        for (int nt = 0; nt < 3; ++nt){
          accD[i][nt] = __builtin_amdgcn_mfma_f32_16x16x32_bf16(AH[i], BHf[nt], accD[i][nt], 0, 0, 0);
          accD[i][nt] = __builtin_amdgcn_mfma_f32_16x16x32_bf16(AH[i], BLf[nt], accD[i][nt], 0, 0, 0);
          accD[i][nt] = __builtin_amdgcn_mfma_f32_16x16x32_bf16(AL[i], BHf[nt], accD[i][nt], 0, 0, 0);
        }
    }
  }
  __syncthreads();

  // ---- epilogue D: scale by dR2, re-split, store J2 over Bd ----
  #pragma unroll
  for (int i = 0; i < 4; ++i){
    int mt = 4*w + i;
    int m0 = mt*16 + 4*l4g;
    int bb = m0 & 31;
    #pragma unroll
    for (int nt = 0; nt < 3; ++nt){
      int c = nt*16 + l15;
      int s = c >= 24;
      unsigned word = msk[s][8 + (mt>>1)];
      unsigned short hs[4], ls[4];
      #pragma unroll
      for (int r = 0; r < 4; ++r){
        float sc = ((word >> (bb + r)) & 1u) ? 1.f : -0.01f;
        float v = sc * accD[i][nt][r];
        hs[r] = f2b(v); ls[r] = f2b(v - b2f(hs[r]));
      }
      *(uint2*)(BH + c*264 + m0) = make_uint2((unsigned)hs[0] | ((unsigned)hs[1]<<16),
                                              (unsigned)hs[2] | ((unsigned)hs[3]<<16));
      *(uint2*)(BL + c*264 + m0) = make_uint2((unsigned)ls[0] | ((unsigned)ls[1]<<16),
                                              (unsigned)ls[2] | ((unsigned)ls[3]<<16));
    }
  }
  __syncthreads();

  // ---- Stage E ----
  f32x4 accE[5][3];
  #pragma unroll
  for (int i = 0; i < 5; ++i)
    #pragma unroll
    for (int nt = 0; nt < 3; ++nt) accE[i][nt] = (f32x4){0.f,0.f,0.f,0.f};
  {
    const bf16x8* AHp = (const bf16x8*)(ws + OFF_WEFH);
    const bf16x8* ALp = (const bf16x8*)(ws + OFF_WEFL);
    for (int kb = 0; kb < 8; ++kb){
      bf16x8 AH[5], AL[5], BHf[3], BLf[3];
      #pragma unroll
      for (int i = 0; i < 5; ++i){
        int mt = 5*w + i;
        AH[i] = AHp[(mt*8+kb)*64 + l];
        AL[i] = ALp[(mt*8+kb)*64 + l];
      }
      #pragma unroll
      for (int nt = 0; nt < 3; ++nt){
        int off = (nt*16 + l15)*264 + kb*32 + l4g*8;
        BHf[nt] = *(const bf16x8*)(BH + off);
        BLf[nt] = *(const bf16x8*)(BL + off);
      }
      #pragma unroll
      for (int i = 0; i < 5; ++i)
        #pragma unroll
        for (int nt = 0; nt < 3; ++nt){
          accE[i][nt] = __builtin_amdgcn_mfma_f32_16x16x32_bf16(AH[i], BHf[nt], accE[i][nt], 0, 0, 0);
          accE[i][nt] = __builtin_amdgcn_mfma_f32_16x16x32_bf16(AH[i], BLf[nt], accE[i][nt], 0, 0, 0);
          accE[i][nt] = __builtin_amdgcn_mfma_f32_16x16x32_bf16(AL[i], BHf[nt], accE[i][nt], 0, 0, 0);
        }
    }
  }
  __syncthreads();   // pool free for tail overlay

  // ---- lean fused tails, sample-sequential ----
  for (int s = 0; s < 2; ++s){
    const int n = n0 + s;
    // P1: E-scatter (dld padded, dlo FLAT row-major = faithful buffer) + staging
    #pragma unroll
    for (int i = 0; i < 5; ++i){
      int mt = 5*w + i;
      #pragma unroll
      for (int nt = 0; nt < 3; ++nt){
        int c = nt*16 + l15;
        if ((c >= 24) == (s == 1)){
          int d = c - 24*s;
          #pragma unroll
          for (int r = 0; r < 4; ++r){
            int re = mt*16 + 4*l4g + r;
            if (re < 24) dld25[re*25 + d] = accE[i][nt][r];
            else if (re < 300) dlo_flat[(re-24)*24 + d] = accE[i][nt][r];
          }
        }
      }
    }
    for (int e = t; e < 576; e += 256){
      int a_ = e/24, b_ = e%24;
      int ma = (n*24 + a_) & (NSAMP-1);
      int mb_ = (n*24 + b_) & (NSAMP-1);
      qdm_s[a_*25 + b_] = q_dot[ma*24 + b_];
      um_s[a_*25 + b_]  = UT[a_*NSAMP + mb_];
    }
    if (t < 24){
      sigs[t] = SIGT[t*NSAMP + n];
      qds[t]  = q_dot[n*24 + t];
      uss[t]  = UT[t*NSAMP + n];
    }
    __syncthreads();

    // P2: dt partials (sequential b128: addr = 4*task) + dld_dt
    for (int k = t; k < 1656; k += 256){
      float4 v = *(const float4*)(dlo_flat + 4*k);
      int j4 = (k % 6)*4;
      qp2[k] = v.x*qds[j4] + v.y*qds[j4+1] + v.z*qds[j4+2] + v.w*qds[j4+3];
    }
    if (t < 24){
      float a = 0.f;
      #pragma unroll
      for (int d = 0; d < 24; ++d) a += dld25[t*25+d]*qds[d];
      dtld[t] = sigs[t]*a;
    }
    __syncthreads();

    // P3: dt reduce (grid-stride — 276 > 256!)
    for (int o = t; o < 276; o += 256){
      float a = 0.f;
      #pragma unroll
      for (int j = 0; j < 6; ++j) a += qp2[o*6+j];
      dtlo[o] = a;
    }
    __syncthreads();

    // P4: quad (t<24, compile-time unrolled faithful scan) || w1 (t in [64,88))
    float quad_l = 0.f;
    if (t < 24){
      const int i = t;
      float y[24];
      #pragma unroll
      for (int k = 0; k < 24; ++k) y[k] = um_s[k*25 + i];
      #pragma unroll
      for (int c2 = 0; c2 < 24; ++c2)
        quad_l += y[c2]*qdm_s[i*25+c2]*sigs[c2]*dld25[c2*25+i];
      const float* vb = dlo_flat + i*276;    // faithful flat view: f = i*276 + p
      float4 v4 = (float4){0,0,0,0};
      #pragma unroll
      for (int r = 1; r < 24; ++r){
        float zr = qdm_s[i*25+r];
        #pragma unroll
        for (int cc = 0; cc < r; ++cc){
          const int p = r*(r-1)/2 + cc;
          if ((p & 3) == 0) v4 = *(const float4*)(vb + p);
          float vbv = ((p&3)==0) ? v4.x : ((p&3)==1) ? v4.y : ((p&3)==2) ? v4.z : v4.w;
          quad_l += zr*y[cc]*vbv;
        }
      }
    } else if (t >= 64 && t < 88){
      int i = t - 64;
      float a = qds[i]*dtld[i];
      for (int j = i+1; j < 24; ++j) a += qds[j]*dtlo[j*(j-1)/2 + i];
      w1s[i] = a;
    }
    __syncthreads();

    // P5: c (L row read directly from transposed LOT/LDT)
    if (t < 24){
      const int i = t;
      float cs = dtld[i]*uss[i] + LDT[i*NSAMP + n]*w1s[i];
      for (int k = 0; k < i; ++k){
        int p = i*(i-1)/2 + k;
        cs += LOT[p*NSAMP + n]*w1s[k] + dtlo[p]*uss[k];
      }
      out[C_OFF + n*24 + i] = cs - quad_l;
    }
    __syncthreads();   // before next sample overwrites the overlay
  }
}

extern "C" void kernel_launch(void* const* d_in, const int* in_sizes, int n_in,
                              void* d_out, int out_size, void* d_ws, size_t ws_size,
                              hipStream_t stream)
{
  const float* q   = (const float*)d_in[0];
  const float* qd  = (const float*)d_in[1];
  const float* W1  = (const float*)d_in[2];
  const float* b1  = (const float*)d_in[3];
  const float* W2  = (const float*)d_in[4];
  const float* b2  = (const float*)d_in[5];
  const float* WG  = (const float*)d_in[6];
  const float* bG  = (const float*)d_in[7];
  const float* WLd = (const float*)d_in[8];
  const float* bLd = (const float*)d_in[9];
  const float* WLo = (const float*)d_in[10];
  const float* bLo = (const float*)d_in[11];
  float* out = (float*)d_out;
  float* ws  = (float*)d_ws;

  k0_prep<<<256, 256, 0, stream>>>(W1, W2, WG, WLd, WLo, ws);
  k1_fwd<<<NSAMP/8, 256, 0, stream>>>(q, b1, b2, bG, bLd, bLo, ws, out);
  kU<<<NSAMP/256, 256, 0, stream>>>(qd, ws, ws + OFF_UT);
  kM<<<NSAMP, 256, 0, stream>>>(ws, out);
  kDE<<<NSAMP/2, 256, 0, stream>>>(qd, W1, ws, out);
}

// Round 10
// 254.376 us; speedup vs baseline: 1.3881x; 1.0469x over previous
//
#include <hip/hip_runtime.h>
#include <math.h>

#define DIM 24
#define HID 256
#define NLO 276
#define NSAMP 4096
// output layout: M [4096*576] | c [4096*24] | g [4096*24]
#define C_OFF 2359296
#define G_OFF 2457600

// workspace layout (float offsets)
#define OFF_W2FH 0          // bf16 hi, W2 MFMA-A frags (65536 sh)   32768 f
#define OFF_W2FL 32768      // bf16 lo
#define OFF_WEFH 65536      // bf16 hi, [WLd;WLo;0] frags (81920 sh) 40960 f
#define OFF_WEFL 106496
#define OFF_W1H16 147456    // f16 hi, W1 frags (8192 sh)            4096 f
#define OFF_W1L16 151552
#define OFF_W2H16 155648    // f16 hi, W2 frags (65536 sh)           32768 f
#define OFF_W2L16 188416
#define OFF_WHH16 221184    // f16 hi, heads (Ld|G|Lo|0) frags       43008 f
#define OFF_WHL16 264192
// transposed per-sample fields [field][4096]
#define OFF_MSKT 307200     // 16 u32 words x 4096
#define OFF_SIGT 372736     // 24 x 4096
#define OFF_LDT  471040     // 24 x 4096
#define OFF_UT   569344     // 24 x 4096
#define OFF_LOT  667648     // 276 x 4096
// +/- W1 bf16 split tables, row-major [k][24] (for kDE Bd select)
#define OFF_W1PH 1798144    // 6144 sh = 3072 f each
#define OFF_W1PL 1801216
#define OFF_W1NH 1804288
#define OFF_W1NL 1807360

typedef __attribute__((ext_vector_type(8))) short bf16x8;
typedef __attribute__((ext_vector_type(8))) _Float16 f16x8;
typedef __attribute__((ext_vector_type(4))) float f32x4;

__device__ __forceinline__ float leaky(float x){ return x > 0.f ? x : 0.01f*x; }
__device__ __forceinline__ unsigned short f2b(float f){           // fp32 -> bf16 RNE
  unsigned u = __float_as_uint(f);
  return (unsigned short)((u + 0x7FFFu + ((u >> 16) & 1u)) >> 16);
}
__device__ __forceinline__ float b2f(unsigned short h){ return __uint_as_float(((unsigned)h) << 16); }
__device__ __forceinline__ void f2h2(float v, unsigned short* hi, unsigned short* lo){
  _Float16 h = (_Float16)v;
  _Float16 l = (_Float16)((v - (float)h) * 4096.f);
  *hi = *(unsigned short*)&h; *lo = *(unsigned short*)&l;
}

// ---------------- Kernel 0: fragment packing ----------------
__global__ __launch_bounds__(256) void k0_prep(
    const float* __restrict__ W1, const float* __restrict__ W2,
    const float* __restrict__ WG, const float* __restrict__ WLd,
    const float* __restrict__ WLo, float* __restrict__ ws)
{
  const int tid = blockIdx.x*256 + threadIdx.x;
  const int nth = gridDim.x*256;
  unsigned short* W2FH = (unsigned short*)(ws + OFF_W2FH);
  unsigned short* W2FL = (unsigned short*)(ws + OFF_W2FL);
  for (int e = tid; e < 65536; e += nth){
    int j=e&7, l=(e>>3)&63, kb=(e>>9)&7, mt=e>>12;
    int m = mt*16+(l&15), k = kb*32+((l>>4)&3)*8+j;
    float v = W2[m*256+k];
    unsigned short h = f2b(v);
    W2FH[e]=h; W2FL[e]=f2b(v-b2f(h));
  }
  unsigned short* WEFH = (unsigned short*)(ws + OFF_WEFH);
  unsigned short* WEFL = (unsigned short*)(ws + OFF_WEFL);
  for (int e = tid; e < 81920; e += nth){
    int j=e&7, l=(e>>3)&63, kb=(e>>9)&7, mt=e>>12;
    int r = mt*16+(l&15), k = kb*32+((l>>4)&3)*8+j;
    float v = 0.f;
    if (r < 24) v = WLd[r*256+k]; else if (r < 300) v = WLo[(r-24)*256+k];
    unsigned short h = f2b(v);
    WEFH[e]=h; WEFL[e]=f2b(v-b2f(h));
  }
  unsigned short* W1H = (unsigned short*)(ws + OFF_W1H16);
  unsigned short* W1L = (unsigned short*)(ws + OFF_W1L16);
  for (int e = tid; e < 8192; e += nth){
    int j=e&7, l=(e>>3)&63, mt=e>>9;
    int m = mt*16+(l&15), k = ((l>>4)&3)*8+j;
    float v = (k < 24) ? W1[m*24+k] : 0.f;
    f2h2(v, &W1H[e], &W1L[e]);
  }
  unsigned short* W2H = (unsigned short*)(ws + OFF_W2H16);
  unsigned short* W2L = (unsigned short*)(ws + OFF_W2L16);
  for (int e = tid; e < 65536; e += nth){
    int j=e&7, l=(e>>3)&63, kb=(e>>9)&7, mt=e>>12;
    int m = mt*16+(l&15), k = kb*32+((l>>4)&3)*8+j;
    f2h2(W2[m*256+k], &W2H[e], &W2L[e]);
  }
  unsigned short* WHH = (unsigned short*)(ws + OFF_WHH16);
  unsigned short* WHL = (unsigned short*)(ws + OFF_WHL16);
  for (int e = tid; e < 86016; e += nth){
    int j=e&7, l=(e>>3)&63, kb=(e>>9)&7, mt=e>>12;
    int rr = mt*16+(l&15), k = kb*32+((l>>4)&3)*8+j;
    float v = 0.f;
    if (rr < 24) v = WLd[rr*256+k];
    else if (rr < 48) v = WG[(rr-24)*256+k];
    else if (rr < 324) v = WLo[(rr-48)*256+k];
    f2h2(v, &WHH[e], &WHL[e]);
  }
  // +/- W1 bf16 RNE split tables [k][24]
  unsigned short* W1PH = (unsigned short*)(ws + OFF_W1PH);
  unsigned short* W1PL = (unsigned short*)(ws + OFF_W1PL);
  unsigned short* W1NH = (unsigned short*)(ws + OFF_W1NH);
  unsigned short* W1NL = (unsigned short*)(ws + OFF_W1NL);
  for (int e = tid; e < 6144; e += nth){
    float v = W1[e];
    unsigned short h = f2b(v);
    W1PH[e] = h; W1PL[e] = f2b(v - b2f(h));
    float vn = -0.01f*v;
    unsigned short hn = f2b(vn);
    W1NH[e] = hn; W1NL[e] = f2b(vn - b2f(hn));
  }
}

// ---------------- Kernel 1: MFMA forward + L/M/u (8 samples/block, 512 blocks) ----------------
__global__ __launch_bounds__(256) void k1_fwd(
    const float* __restrict__ q, const float* __restrict__ qd_g,
    const float* __restrict__ b1, const float* __restrict__ b2,
    const float* __restrict__ bG, const float* __restrict__ bLd,
    const float* __restrict__ bLo, float* __restrict__ ws,
    float* __restrict__ out)
{
  const int s0 = blockIdx.x*8, t = threadIdx.x;
  const int w = t>>6, l = t&63, l15 = l&15, l4g = (l>>4)&3;
  unsigned* MSKT = (unsigned*)(ws + OFF_MSKT);
  float* SIGT = ws + OFF_SIGT;
  float* LDT  = ws + OFF_LDT;
  float* UT   = ws + OFF_UT;
  float* LOT  = ws + OFF_LOT;

  __shared__ __align__(16) unsigned short pool[8448];  // BQ (640 sh) -> BH2|BL2 (8448 sh)
  __shared__ unsigned char mb[8][64];
  __shared__ float qd_s[8][24];
  __shared__ float Lsm[8][600];          // per-sample L, stride 25 (diag + strict lower)
  unsigned short* BQH = pool;            // [8][40] f16
  unsigned short* BQL = BQH + 320;
  unsigned short* BH2 = pool;            // [8][264] f16
  unsigned short* BL2 = BH2 + 2112;

  for (int f = t; f < 192; f += 256){
    float v = q[s0*24 + f];
    int n = f/24, k = f%24;
    f2h2(v, &BQH[n*40+k], &BQL[n*40+k]);
    ((float*)qd_s)[f] = qd_g[s0*24 + f];
  }
  if (t < 64){ int n = t>>3, k = 24 + (t&7); BQH[n*40+k]=0; BQL[n*40+k]=0; }
  __syncthreads();

  // ---- phase A: h1 pre-acts = W1 @ qT ----
  f32x4 aH[4], aX[4];
  #pragma unroll
  for (int i=0;i<4;++i){ aH[i]=(f32x4){0,0,0,0}; aX[i]=(f32x4){0,0,0,0}; }
  {
    const f16x8* WH = (const f16x8*)(ws + OFF_W1H16);
    const f16x8* WL = (const f16x8*)(ws + OFF_W1L16);
    f16x8 Af[4], Al[4];
    #pragma unroll
    for (int i=0;i<4;++i){ int mt=w+4*i; Af[i]=WH[mt*64+l]; Al[i]=WL[mt*64+l]; }
    int off = l15*40 + l4g*8;
    f16x8 Bh = *(const f16x8*)(BQH+off), Bl = *(const f16x8*)(BQL+off);
    #pragma unroll
    for (int i=0;i<4;++i){
      aH[i]=__builtin_amdgcn_mfma_f32_16x16x32_f16(Af[i],Bh,aH[i],0,0,0);
      aX[i]=__builtin_amdgcn_mfma_f32_16x16x32_f16(Af[i],Bl,aX[i],0,0,0);
      aX[i]=__builtin_amdgcn_mfma_f32_16x16x32_f16(Al[i],Bh,aX[i],0,0,0);
    }
  }
  __syncthreads();
  #pragma unroll
  for (int i=0;i<4;++i){
    int m0=(w+4*i)*16+4*l4g;
    float4 bb = *(const float4*)(b1+m0);
    int n = l15;
    if (n < 8){
      unsigned nib=0; unsigned short hs[4], ls[4];
      #pragma unroll
      for (int r=0;r<4;++r){
        float val = aH[i][r] + aX[i][r]*(1.f/4096.f) + ((const float*)&bb)[r];
        if (val > 0.f) nib |= 1u<<r;
        f2h2(leaky(val), &hs[r], &ls[r]);
      }
      mb[n][(m0>>2)] = (unsigned char)nib;
      *(uint2*)(BH2 + n*264 + m0) = make_uint2((unsigned)hs[0]|((unsigned)hs[1]<<16),
                                               (unsigned)hs[2]|((unsigned)hs[3]<<16));
      *(uint2*)(BL2 + n*264 + m0) = make_uint2((unsigned)ls[0]|((unsigned)ls[1]<<16),
                                               (unsigned)ls[2]|((unsigned)ls[3]<<16));
    }
  }
  __syncthreads();
  if (t < 64){ // msk1 -> MSKT
    int n = t&7, w8 = t>>3; unsigned word = 0;
    #pragma unroll
    for (int b=0;b<8;++b) word |= (unsigned)(mb[n][w8*8+b] & 0xFu) << (4*b);
    MSKT[w8*NSAMP + s0+n] = word;
  }

  // ---- phase B: h2 = W2 @ h1 ----
  #pragma unroll
  for (int i=0;i<4;++i){ aH[i]=(f32x4){0,0,0,0}; aX[i]=(f32x4){0,0,0,0}; }
  {
    const f16x8* WH = (const f16x8*)(ws + OFF_W2H16);
    const f16x8* WL = (const f16x8*)(ws + OFF_W2L16);
    for (int kb=0;kb<8;++kb){
      f16x8 Af[4], Al[4];
      #pragma unroll
      for (int i=0;i<4;++i){ int mt=w+4*i; Af[i]=WH[(mt*8+kb)*64+l]; Al[i]=WL[(mt*8+kb)*64+l]; }
      int off = l15*264 + kb*32 + l4g*8;
      f16x8 Bh = *(const f16x8*)(BH2+off), Bl = *(const f16x8*)(BL2+off);
      #pragma unroll
      for (int i=0;i<4;++i){
        aH[i]=__builtin_amdgcn_mfma_f32_16x16x32_f16(Af[i],Bh,aH[i],0,0,0);
        aX[i]=__builtin_amdgcn_mfma_f32_16x16x32_f16(Af[i],Bl,aX[i],0,0,0);
        aX[i]=__builtin_amdgcn_mfma_f32_16x16x32_f16(Al[i],Bh,aX[i],0,0,0);
      }
    }
  }
  __syncthreads();
  #pragma unroll
  for (int i=0;i<4;++i){
    int m0=(w+4*i)*16+4*l4g;
    float4 bb = *(const float4*)(b2+m0);
    int n = l15;
    if (n < 8){
      unsigned nib=0; unsigned short hs[4], ls[4];
      #pragma unroll
      for (int r=0;r<4;++r){
        float val = aH[i][r] + aX[i][r]*(1.f/4096.f) + ((const float*)&bb)[r];
        if (val > 0.f) nib |= 1u<<r;
        f2h2(leaky(val), &hs[r], &ls[r]);
      }
      mb[n][(m0>>2)] = (unsigned char)nib;
      *(uint2*)(BH2 + n*264 + m0) = make_uint2((unsigned)hs[0]|((unsigned)hs[1]<<16),
                                               (unsigned)hs[2]|((unsigned)hs[3]<<16));
      *(uint2*)(BL2 + n*264 + m0) = make_uint2((unsigned)ls[0]|((unsigned)ls[1]<<16),
                                               (unsigned)ls[2]|((unsigned)ls[3]<<16));
    }
  }
  __syncthreads();
  if (t < 64){ // msk2 -> MSKT
    int n = t&7, w8 = t>>3; unsigned word = 0;
    #pragma unroll
    for (int b=0;b<8;++b) word |= (unsigned)(mb[n][w8*8+b] & 0xFu) << (4*b);
    MSKT[(8+w8)*NSAMP + s0+n] = word;
  }

  // ---- phase C: heads = [WLd;WG;WLo;0] @ h2 ----
  for (int pass=0; pass<2; ++pass){
    f32x4 cH[3], cX[3];
    #pragma unroll
    for (int i=0;i<3;++i){ cH[i]=(f32x4){0,0,0,0}; cX[i]=(f32x4){0,0,0,0}; }
    const f16x8* WH = (const f16x8*)(ws + OFF_WHH16);
    const f16x8* WL = (const f16x8*)(ws + OFF_WHL16);
    for (int kb=0;kb<8;++kb){
      f16x8 Af[3], Al[3];
      #pragma unroll
      for (int i=0;i<3;++i){
        int mt = w + 4*(3*pass+i);
        if (mt < 21){ Af[i]=WH[(mt*8+kb)*64+l]; Al[i]=WL[(mt*8+kb)*64+l]; }
      }
      int off = l15*264 + kb*32 + l4g*8;
      f16x8 Bh = *(const f16x8*)(BH2+off), Bl = *(const f16x8*)(BL2+off);
      #pragma unroll
      for (int i=0;i<3;++i){
        int mt = w + 4*(3*pass+i);
        if (mt < 21){
          cH[i]=__builtin_amdgcn_mfma_f32_16x16x32_f16(Af[i],Bh,cH[i],0,0,0);
          cX[i]=__builtin_amdgcn_mfma_f32_16x16x32_f16(Af[i],Bl,cX[i],0,0,0);
          cX[i]=__builtin_amdgcn_mfma_f32_16x16x32_f16(Al[i],Bh,cX[i],0,0,0);
        }
      }
    }
    #pragma unroll
    for (int i=0;i<3;++i){
      int mt = w + 4*(3*pass+i);
      if (mt >= 21) continue;
      int m0 = mt*16+4*l4g;
      int n = l15;
      if (n < 8){
        int sG = s0+n;
        // incremental tri decode for lo tiles (m0 >= 48 -> whole mini-run is lo)
        int tr = 0, tc = 0;
        if (m0 >= 48){
          int p = m0 - 48;
          tr = (int)((1.f + sqrtf(1.f + 8.f*(float)p))*0.5f);
          while (tr*(tr-1)/2 > p) --tr;
          while ((tr+1)*tr/2 <= p) ++tr;
          tc = p - tr*(tr-1)/2;
        }
        #pragma unroll
        for (int r=0;r<4;++r){
          int rr = m0+r;
          float val = cH[i][r] + cX[i][r]*(1.f/4096.f);
          if (rr < 24){
            val += bLd[rr];
            SIGT[rr*NSAMP + sG] = 1.f/(1.f + expf(-val));
            float sp = fmaxf(val,0.f) + log1pf(expf(-fabsf(val)));
            LDT[rr*NSAMP + sG] = sp;
            Lsm[n][rr*25 + rr] = sp;
          } else if (rr < 48){
            out[G_OFF + sG*24 + (rr-24)] = val + bG[rr-24];
          } else if (rr < 324){
            float lov = val + bLo[rr-48];
            LOT[(rr-48)*NSAMP + sG] = lov;
            Lsm[n][tr*25 + tc] = lov;
            if (++tc == tr){ ++tr; tc = 0; }
          }
        }
      }
    }
  }
  __syncthreads();

  // ---- M = L L^T + 1e-9 I (8 samples) ----
  for (int n2 = 0; n2 < 8; ++n2){
    const float* Ls = Lsm[n2];
    for (int e = t; e < 576; e += 256){
      int r = e/24, c = e%24, km = min(r,c);
      float acc = (r == c) ? 1e-9f : 0.f;
      for (int k = 0; k <= km; ++k) acc += Ls[r*25+k]*Ls[c*25+k];
      out[(size_t)(s0+n2)*576 + e] = acc;
    }
  }
  // ---- u[c] = qd[c]*L[c,c] + sum_{r>c} qd[r]*L[r,c] ----
  if (t < 192){
    int n = t/24, c = t%24;
    float u = qd_s[n][c]*Lsm[n][c*25+c];
    for (int r = c+1; r < 24; ++r) u += qd_s[n][r]*Lsm[n][r*25+c];
    UT[c*NSAMP + s0+n] = u;
  }
}

// ---------------- Kernel DE: MFMA Jacobian GEMMs + lean tails (2 samples/block) ----------------
__global__ __launch_bounds__(256, 3) void kDE(
    const float* __restrict__ q_dot, float* __restrict__ ws, float* __restrict__ out)
{
  const int n0 = blockIdx.x*2, t = threadIdx.x;
  const int w = t >> 6, l = t & 63;
  const int l15 = l & 15, l4g = (l >> 4) & 3;
  const unsigned* MSKT = (const unsigned*)(ws + OFF_MSKT);
  const float* SIGT = ws + OFF_SIGT;
  const float* LDT  = ws + OFF_LDT;
  const float* UT   = ws + OFF_UT;
  const float* LOT  = ws + OFF_LOT;

  // pool: [BH|BL] bf16 (50688 B) during GEMMs; tail overlay after
  __shared__ __align__(16) char pool[50688];
  __shared__ unsigned msk[2][16];
  unsigned short* BH = (unsigned short*)pool;
  unsigned short* BL = BH + 12672;
  // tail overlay
  float* dlo_flat = (float*)pool;            // [276*24] flat (faithful view) 26496 B
  float* dld25    = (float*)(pool + 26496);  // [24][25]
  float* qdm_s    = (float*)(pool + 28896);  // [24][25]
  float* um_s     = (float*)(pool + 31296);  // [24][25]
  float* qp2      = (float*)(pool + 33696);  // [1656] dt partials
  float* dtlo     = (float*)(pool + 40320);  // [276]
  float* dtld     = (float*)(pool + 41424);  // [24]
  float* w1s      = (float*)(pool + 41520);  // [24]
  float* sigs     = (float*)(pool + 41616);  // [24]
  float* qds      = (float*)(pool + 41712);  // [24]
  float* uss      = (float*)(pool + 41808);  // [24]
  float* qps      = (float*)(pool + 41904);  // [4][24] quad partials

  if (t < 32) msk[t>>4][t&15] = MSKT[(t&15)*NSAMP + n0 + (t>>4)];
  __syncthreads();

  // ---- Bd build: per-k select from precomputed +/-W1 split tables ----
  {
    bool p0 = (msk[0][t>>5] >> (t&31)) & 1u;
    bool p1 = (msk[1][t>>5] >> (t&31)) & 1u;
    const unsigned* h0 = (const unsigned*)((const unsigned short*)(ws + (p0 ? OFF_W1PH : OFF_W1NH)) + t*24);
    const unsigned* l0 = (const unsigned*)((const unsigned short*)(ws + (p0 ? OFF_W1PL : OFF_W1NL)) + t*24);
    const unsigned* h1 = (const unsigned*)((const unsigned short*)(ws + (p1 ? OFF_W1PH : OFF_W1NH)) + t*24);
    const unsigned* l1 = (const unsigned*)((const unsigned short*)(ws + (p1 ? OFF_W1PL : OFF_W1NL)) + t*24);
    #pragma unroll
    for (int j = 0; j < 12; ++j){
      unsigned dh0 = h0[j], dl0 = l0[j], dh1 = h1[j], dl1 = l1[j];
      BH[(2*j)*264 + t]      = (unsigned short)dh0;
      BH[(2*j+1)*264 + t]    = (unsigned short)(dh0 >> 16);
      BL[(2*j)*264 + t]      = (unsigned short)dl0;
      BL[(2*j+1)*264 + t]    = (unsigned short)(dl0 >> 16);
      BH[(24+2*j)*264 + t]   = (unsigned short)dh1;
      BH[(24+2*j+1)*264 + t] = (unsigned short)(dh1 >> 16);
      BL[(24+2*j)*264 + t]   = (unsigned short)dl1;
      BL[(24+2*j+1)*264 + t] = (unsigned short)(dl1 >> 16);
    }
  }
  __syncthreads();

  // ---- Stage D ----
  f32x4 accD[4][3];
  #pragma unroll
  for (int i = 0; i < 4; ++i)
    #pragma unroll
    for (int nt = 0; nt < 3; ++nt) accD[i][nt] = (f32x4){0.f,0.f,0.f,0.f};
  {
    const bf16x8* AHp = (const bf16x8*)(ws + OFF_W2FH);
    const bf16x8* ALp = (const bf16x8*)(ws + OFF_W2FL);
    for (int kb = 0; kb < 8; ++kb){
      bf16x8 AH[4], AL[4], BHf[3], BLf[3];
      #pragma unroll
      for (int i = 0; i < 4; ++i){
        int mt = 4*w + i;
        AH[i] = AHp[(mt*8+kb)*64 + l];
        AL[i] = ALp[(mt*8+kb)*64 + l];
      }
      #pragma unroll
      for (int nt = 0; nt < 3; ++nt){
        int off = (nt*16 + l15)*264 + kb*32 + l4g*8;
        BHf[nt] = *(const bf16x8*)(BH + off);
        BLf[nt] = *(const bf16x8*)(BL + off);
      }
      #pragma unroll
      for (int i = 0; i < 4; ++i)
        #pragma unroll
        for (int nt = 0; nt < 3; ++nt){
          accD[i][nt] = __builtin_amdgcn_mfma_f32_16x16x32_bf16(AH[i], BHf[nt], accD[i][nt], 0, 0, 0);
          accD[i][nt] = __builtin_amdgcn_mfma_f32_16x16x32_bf16(AH[i], BLf[nt], accD[i][nt], 0, 0, 0);
          accD[i][nt] = __builtin_amdgcn_mfma_f32_16x16x32_bf16(AL[i], BHf[nt], accD[i][nt], 0, 0, 0);
        }
    }
  }
  __syncthreads();

  // ---- epilogue D: scale by dR2, truncation split, store J2 over Bd ----
  #pragma unroll
  for (int i = 0; i < 4; ++i){
    int mt = 4*w + i;
    int m0 = mt*16 + 4*l4g;
    int bb = m0 & 31;
    #pragma unroll
    for (int nt = 0; nt < 3; ++nt){
      int c = nt*16 + l15;
      int s = c >= 24;
      unsigned word = msk[s][8 + (mt>>1)];
      unsigned uh[4], ul[4];
      #pragma unroll
      for (int r = 0; r < 4; ++r){
        float sc = ((word >> (bb + r)) & 1u) ? 1.f : -0.01f;
        float v = sc * accD[i][nt][r];
        unsigned uv = __float_as_uint(v);
        uh[r] = uv;
        float lo = v - __uint_as_float(uv & 0xFFFF0000u);
        ul[r] = __float_as_uint(lo);
      }
      *(uint2*)(BH + c*264 + m0) = make_uint2((uh[0]>>16) | (uh[1] & 0xFFFF0000u),
                                              (uh[2]>>16) | (uh[3] & 0xFFFF0000u));
      *(uint2*)(BL + c*264 + m0) = make_uint2((ul[0]>>16) | (ul[1] & 0xFFFF0000u),
                                              (ul[2]>>16) | (ul[3] & 0xFFFF0000u));
    }
  }
  __syncthreads();

  // ---- Stage E ----
  f32x4 accE[5][3];
  #pragma unroll
  for (int i = 0; i < 5; ++i)
    #pragma unroll
    for (int nt = 0; nt < 3; ++nt) accE[i][nt] = (f32x4){0.f,0.f,0.f,0.f};
  {
    const bf16x8* AHp = (const bf16x8*)(ws + OFF_WEFH);
    const bf16x8* ALp = (const bf16x8*)(ws + OFF_WEFL);
    for (int kb = 0; kb < 8; ++kb){
      bf16x8 AH[5], AL[5], BHf[3], BLf[3];
      #pragma unroll
      for (int i = 0; i < 5; ++i){
        int mt = 5*w + i;
        AH[i] = AHp[(mt*8+kb)*64 + l];
        AL[i] = ALp[(mt*8+kb)*64 + l];
      }
      #pragma unroll
      for (int nt = 0; nt < 3; ++nt){
        int off = (nt*16 + l15)*264 + kb*32 + l4g*8;
        BHf[nt] = *(const bf16x8*)(BH + off);
        BLf[nt] = *(const bf16x8*)(BL + off);
      }
      #pragma unroll
      for (int i = 0; i < 5; ++i)
        #pragma unroll
        for (int nt = 0; nt < 3; ++nt){
          accE[i][nt] = __builtin_amdgcn_mfma_f32_16x16x32_bf16(AH[i], BHf[nt], accE[i][nt], 0, 0, 0);
          accE[i][nt] = __builtin_amdgcn_mfma_f32_16x16x32_bf16(AH[i], BLf[nt], accE[i][nt], 0, 0, 0);
          accE[i][nt] = __builtin_amdgcn_mfma_f32_16x16x32_bf16(AL[i], BHf[nt], accE[i][nt], 0, 0, 0);
        }
    }
  }
  __syncthreads();   // pool free for tail overlay

  // ---- lean fused tails, sample-sequential ----
  for (int s = 0; s < 2; ++s){
    const int n = n0 + s;
    // P1: E-scatter + staging
    #pragma unroll
    for (int i = 0; i < 5; ++i){
      int mt = 5*w + i;
      #pragma unroll
      for (int nt = 0; nt < 3; ++nt){
        int c = nt*16 + l15;
        if ((c >= 24) == (s == 1)){
          int d = c - 24*s;
          #pragma unroll
          for (int r = 0; r < 4; ++r){
            int re = mt*16 + 4*l4g + r;
            if (re < 24) dld25[re*25 + d] = accE[i][nt][r];
            else if (re < 300) dlo_flat[(re-24)*24 + d] = accE[i][nt][r];
          }
        }
      }
    }
    for (int e = t; e < 576; e += 256){
      int a_ = e/24, b_ = e%24;
      int ma = (n*24 + a_) & (NSAMP-1);
      int mb_ = (n*24 + b_) & (NSAMP-1);
      qdm_s[a_*25 + b_] = q_dot[ma*24 + b_];
      um_s[a_*25 + b_]  = UT[a_*NSAMP + mb_];
    }
    if (t < 24){
      sigs[t] = SIGT[t*NSAMP + n];
      qds[t]  = q_dot[n*24 + t];
      uss[t]  = UT[t*NSAMP + n];
    }
    __syncthreads();

    // P2: dt partials (sequential b128) + dld_dt
    for (int k = t; k < 1656; k += 256){
      float4 v = *(const float4*)(dlo_flat + 4*k);
      int j4 = (k % 6)*4;
      qp2[k] = v.x*qds[j4] + v.y*qds[j4+1] + v.z*qds[j4+2] + v.w*qds[j4+3];
    }
    if (t < 24){
      float a = 0.f;
      #pragma unroll
      for (int d = 0; d < 24; ++d) a += dld25[t*25+d]*qds[d];
      dtld[t] = sigs[t]*a;
    }
    __syncthreads();

    // P3: dt reduce (grid-stride)
    for (int o = t; o < 276; o += 256){
      float a = 0.f;
      #pragma unroll
      for (int j = 0; j < 6; ++j) a += qp2[o*6+j];
      dtlo[o] = a;
    }
    __syncthreads();

    // P4: quad partials (t<96: 4 stripes x 24 i) || w1 (t in [128,152))
    if (t < 96){
      int g = t/24, i = t%24;
      float part = 0.f;
      for (int c2 = g; c2 < 24; c2 += 4){
        float v = qdm_s[i*25+c2]*sigs[c2]*dld25[c2*25+i];
        for (int r = c2+1; r < 24; ++r){
          int p = r*(r-1)/2 + c2;                 // faithful flat view: f = i*276 + p
          v += qdm_s[i*25+r]*dlo_flat[i*276 + p];
        }
        part += um_s[c2*25+i]*v;
      }
      qps[g*24 + i] = part;
    } else if (t >= 128 && t < 152){
      int i = t - 128;
      float a = qds[i]*dtld[i];
      for (int j = i+1; j < 24; ++j) a += qds[j]*dtlo[j*(j-1)/2 + i];
      w1s[i] = a;
    }
    __syncthreads();

    // P5: c
    if (t < 24){
      const int i = t;
      float cs = dtld[i]*uss[i] + LDT[i*NSAMP + n]*w1s[i];
      for (int k = 0; k < i; ++k){
        int p = i*(i-1)/2 + k;
        cs += LOT[p*NSAMP + n]*w1s[k] + dtlo[p]*uss[k];
      }
      float quad = qps[i] + qps[24+i] + qps[48+i] + qps[72+i];
      out[C_OFF + n*24 + i] = cs - quad;
    }
    __syncthreads();   // before next sample overwrites the overlay
  }
}

extern "C" void kernel_launch(void* const* d_in, const int* in_sizes, int n_in,
                              void* d_out, int out_size, void* d_ws, size_t ws_size,
                              hipStream_t stream)
{
  const float* q   = (const float*)d_in[0];
  const float* qd  = (const float*)d_in[1];
  const float* W1  = (const float*)d_in[2];
  const float* b1  = (const float*)d_in[3];
  const float* W2  = (const float*)d_in[4];
  const float* b2  = (const float*)d_in[5];
  const float* WG  = (const float*)d_in[6];
  const float* bG  = (const float*)d_in[7];
  const float* WLd = (const float*)d_in[8];
  const float* bLd = (const float*)d_in[9];
  const float* WLo = (const float*)d_in[10];
  const float* bLo = (const float*)d_in[11];
  float* out = (float*)d_out;
  float* ws  = (float*)d_ws;

  k0_prep<<<256, 256, 0, stream>>>(W1, W2, WG, WLd, WLo, ws);
  k1_fwd<<<NSAMP/8, 256, 0, stream>>>(q, qd, b1, b2, bG, bLd, bLo, ws, out);
  kDE<<<NSAMP/2, 256, 0, stream>>>(qd, ws, out);
}